// Round 2
// baseline (487.865 us; speedup 1.0000x reference)
//
#include <hip/hip_runtime.h>

#define BB 4
#define SLQ 1024
#define SLK 2048
#define EE 512
#define HH 8
#define HD 64

typedef unsigned short u16;
typedef __attribute__((ext_vector_type(8))) short s16x8;
typedef __attribute__((ext_vector_type(4))) short s16x4;
typedef __attribute__((ext_vector_type(4))) float f32x4;

__device__ __forceinline__ float bf2f(u16 u) {
  union { unsigned int i; float f; } v; v.i = ((unsigned int)u) << 16; return v.f;
}
__device__ __forceinline__ u16 f2bf(float f) {
  union { float f; unsigned int i; } v; v.f = f;
  unsigned int i = v.i;
  return (u16)((i + 0x7fffu + ((i >> 16) & 1u)) >> 16);
}

__device__ __forceinline__ void async16(const u16* g, u16* l) {
  __builtin_amdgcn_global_load_lds(
      (const __attribute__((address_space(1))) unsigned int*)g,
      (__attribute__((address_space(3))) unsigned int*)l, 16, 0, 0);
}

// NT GEMM: C[m,n] = alpha * sum_k A[m,k]*B[n,k] + bias[n]   (A,B bf16; bias f32)
// MODE 0: C + z*sCz, row-major ldc
// MODE 1: head-split store [B,H,Lsub,64]  (for Q/K projections)
// MODE 2: head-split transposed [B,H,64,Lsub] (for V projections)
// MODE 3: attention-out store: C + (z/8)*SLQ*EE + m*EE + (z%8)*64 + n
template<int BM, int BN, int MODE>
__global__ __launch_bounds__(256, 2)
void gemm_nt(const u16* __restrict__ A, const u16* __restrict__ Bm,
             const float* __restrict__ bias, u16* __restrict__ C,
             int M, int N, int K, int lda, int ldb, int ldc,
             long sAz, long sBz, long sCz, float alpha, int Lsub)
{
  constexpr int WTM = BM / 2, WTN = BN / 2;
  constexpr int MI = WTM / 16, NI = WTN / 16;

  __shared__ __align__(16) u16 ldsA[BM * 32];
  __shared__ __align__(16) u16 ldsB[BN * 32];

  const int t = threadIdx.x;
  const int lane = t & 63;
  const int wave = t >> 6;
  const int waveM = wave >> 1;
  const int waveN = wave & 1;
  const int lm = lane & 15;
  const int kg = lane >> 4;

  const int z = blockIdx.z;
  const int tileM = blockIdx.y * BM;
  const int tileN = blockIdx.x * BN;

  const u16* Ab = A + (long)z * sAz + (long)tileM * lda;
  const u16* Bb = Bm + (long)z * sBz + (long)tileN * ldb;

  f32x4 acc[MI][NI];
#pragma unroll
  for (int i = 0; i < MI; ++i)
#pragma unroll
    for (int j = 0; j < NI; ++j) acc[i][j] = (f32x4){0.f, 0.f, 0.f, 0.f};

  for (int kt = 0; kt < K; kt += 32) {
    __syncthreads();
#pragma unroll
    for (int i = 0; i < (BM * 4) / 256; ++i) {
      int c = i * 256 + t;
      async16(Ab + (long)(c >> 2) * lda + kt + (c & 3) * 8, ldsA + (c - lane) * 8);
    }
#pragma unroll
    for (int i = 0; i < (BN * 4) / 256; ++i) {
      int c = i * 256 + t;
      async16(Bb + (long)(c >> 2) * ldb + kt + (c & 3) * 8, ldsB + (c - lane) * 8);
    }
    __syncthreads();

    s16x8 aF[MI], bF[NI];
#pragma unroll
    for (int i = 0; i < MI; ++i)
      aF[i] = *(const s16x8*)&ldsA[(waveM * WTM + i * 16 + lm) * 32 + kg * 8];
#pragma unroll
    for (int j = 0; j < NI; ++j)
      bF[j] = *(const s16x8*)&ldsB[(waveN * WTN + j * 16 + lm) * 32 + kg * 8];
#pragma unroll
    for (int i = 0; i < MI; ++i)
#pragma unroll
      for (int j = 0; j < NI; ++j)
        acc[i][j] = __builtin_amdgcn_mfma_f32_16x16x32_bf16(aF[i], bF[j], acc[i][j], 0, 0, 0);
  }

#pragma unroll
  for (int j = 0; j < NI; ++j) {
    int n = tileN + waveN * WTN + j * 16 + lm;
    float bv = bias ? bias[n] : 0.0f;
#pragma unroll
    for (int i = 0; i < MI; ++i) {
#pragma unroll
      for (int r = 0; r < 4; ++r) {
        int m = tileM + waveM * WTM + i * 16 + kg * 4 + r;
        float v = acc[i][j][r] * alpha + bv;
        if (MODE == 0) {
          C[(long)z * sCz + (long)m * ldc + n] = f2bf(v);
        } else if (MODE == 1) {
          int b = m / Lsub, l = m - b * Lsub;
          int h = n >> 6, d = n & 63;
          C[(((long)(b * HH + h) * Lsub + l) << 6) + d] = f2bf(v);
        } else if (MODE == 2) {
          int b = m / Lsub, l = m - b * Lsub;
          int h = n >> 6, d = n & 63;
          C[((long)(b * HH + h) * HD + d) * Lsub + l] = f2bf(v);
        } else {
          int b = z >> 3, h = z & 7;
          C[(long)b * SLQ * EE + (long)m * EE + h * HD + n] = f2bf(v);
        }
      }
    }
  }
}

// f32 -> bf16 conversion, 8 elems/thread
__global__ __launch_bounds__(256)
void cvt_kernel(const float* __restrict__ in, u16* __restrict__ out) {
  long base = ((long)blockIdx.x * 256 + threadIdx.x) * 8;
  float4 a = *(const float4*)&in[base];
  float4 b = *(const float4*)&in[base + 4];
  s16x8 o;
  o[0] = (short)f2bf(a.x); o[1] = (short)f2bf(a.y);
  o[2] = (short)f2bf(a.z); o[3] = (short)f2bf(a.w);
  o[4] = (short)f2bf(b.x); o[5] = (short)f2bf(b.y);
  o[6] = (short)f2bf(b.z); o[7] = (short)f2bf(b.w);
  *(s16x8*)&out[base] = o;
}

// queries f32 -> masked bf16 q0
__global__ __launch_bounds__(256)
void mask_q_kernel(const float* __restrict__ in, u16* __restrict__ out,
                   const int* __restrict__ qlen) {
  long base = ((long)blockIdx.x * 256 + threadIdx.x) * 8;
  int row = (int)(base >> 9);       // /512
  int b = row >> 10, q = row & 1023;
  s16x8 o = (s16x8){0, 0, 0, 0, 0, 0, 0, 0};
  if (q < qlen[b]) {
    float4 a = *(const float4*)&in[base];
    float4 c = *(const float4*)&in[base + 4];
    o[0] = (short)f2bf(a.x); o[1] = (short)f2bf(a.y);
    o[2] = (short)f2bf(a.z); o[3] = (short)f2bf(a.w);
    o[4] = (short)f2bf(c.x); o[5] = (short)f2bf(c.y);
    o[6] = (short)f2bf(c.z); o[7] = (short)f2bf(c.w);
  }
  *(s16x8*)&out[base] = o;
}

__device__ __forceinline__ float blockSum(float v, float* red4) {
#pragma unroll
  for (int o = 32; o; o >>= 1) v += __shfl_xor(v, o);
  if ((threadIdx.x & 63) == 0) red4[threadIdx.x >> 6] = v;
  __syncthreads();
  v = red4[0] + red4[1] + red4[2] + red4[3];
  __syncthreads();
  return v;
}
__device__ __forceinline__ float blockMax(float v, float* red4) {
#pragma unroll
  for (int o = 32; o; o >>= 1) v = fmaxf(v, __shfl_xor(v, o));
  if ((threadIdx.x & 63) == 0) red4[threadIdx.x >> 6] = v;
  __syncthreads();
  v = fmaxf(fmaxf(red4[0], red4[1]), fmaxf(red4[2], red4[3]));
  __syncthreads();
  return v;
}

// cross softmax: rows of LK=2048, no key mask; invalid q rows -> 0
__global__ __launch_bounds__(256)
void softmax_cross_kernel(u16* __restrict__ S, const int* __restrict__ qlen) {
  int row = blockIdx.x;            // [0, B*H*LQ)
  int z = row >> 10, q = row & 1023, b = z >> 3;
  u16* p = S + (long)row * SLK;
  int t = threadIdx.x;
  if (q >= qlen[b]) { *(uint4*)&p[t * 8] = (uint4){0, 0, 0, 0}; return; }
  __shared__ float red4[4];
  s16x8 v = *(const s16x8*)&p[t * 8];
  float x[8]; float m = -1e30f;
#pragma unroll
  for (int j = 0; j < 8; ++j) { x[j] = bf2f((u16)v[j]); m = fmaxf(m, x[j]); }
  m = blockMax(m, red4);
  float s = 0.f;
#pragma unroll
  for (int j = 0; j < 8; ++j) { x[j] = __expf(fmaxf(x[j] - m, -80.f)); s += x[j]; }
  s = blockSum(s, red4);
  float r = 1.0f / s;
#pragma unroll
  for (int j = 0; j < 8; ++j) v[j] = (short)f2bf(x[j] * r);
  *(s16x8*)&p[t * 8] = v;
}

// self softmax: rows of LQ=1024, keys masked to k<qlen[b]; invalid q rows -> 0
__global__ __launch_bounds__(256)
void softmax_self_kernel(u16* __restrict__ S, const int* __restrict__ qlen) {
  int row = blockIdx.x;
  int z = row >> 10, q = row & 1023, b = z >> 3;
  u16* p = S + (long)row * SLQ;
  int t = threadIdx.x;
  int nvalid = qlen[b];
  if (q >= nvalid) { *(uint2*)&p[t * 4] = (uint2){0, 0}; return; }
  __shared__ float red4[4];
  s16x4 v = *(const s16x4*)&p[t * 4];
  float x[4]; float m = -1e30f;
#pragma unroll
  for (int j = 0; j < 4; ++j) {
    int k = t * 4 + j;
    x[j] = (k < nvalid) ? bf2f((u16)v[j]) : -1e30f;
    m = fmaxf(m, x[j]);
  }
  m = blockMax(m, red4);
  float s = 0.f;
#pragma unroll
  for (int j = 0; j < 4; ++j) { x[j] = __expf(fmaxf(x[j] - m, -80.f)); s += x[j]; }
  s = blockSum(s, red4);
  float r = 1.0f / s;
#pragma unroll
  for (int j = 0; j < 4; ++j) v[j] = (short)f2bf(x[j] * r);
  *(s16x4*)&p[t * 4] = v;
}

// weights output: mean over 8 heads of softmaxed S -> f32
__global__ __launch_bounds__(256)
void wmean_kernel(const u16* __restrict__ S, float* __restrict__ out) {
  long i = (long)blockIdx.x * 256 + threadIdx.x;
  long base = i * 8;                       // into [B][LQ][LK]
  int b = (int)(base / ((long)SLQ * SLK));
  long rem = base - (long)b * SLQ * SLK;
  float acc[8] = {0, 0, 0, 0, 0, 0, 0, 0};
#pragma unroll
  for (int h = 0; h < HH; ++h) {
    s16x8 v = *(const s16x8*)(S + (long)(b * HH + h) * SLQ * SLK + rem);
#pragma unroll
    for (int j = 0; j < 8; ++j) acc[j] += bf2f((u16)v[j]);
  }
  float4 o0 = {acc[0] * 0.125f, acc[1] * 0.125f, acc[2] * 0.125f, acc[3] * 0.125f};
  float4 o1 = {acc[4] * 0.125f, acc[5] * 0.125f, acc[6] * 0.125f, acc[7] * 0.125f};
  *(float4*)&out[base] = o0;
  *(float4*)&out[base + 4] = o1;
}

// out = LN(silu(x1+x2)) * g + beta; x1,x2 bf16; g,beta f32.
// OUTF32=0 -> bf16 out; OUTF32=1 -> f32 out. maskOut zeroes invalid rows.
template<int OUTF32>
__global__ __launch_bounds__(256)
void silu_ln_kernel(const u16* __restrict__ x1, const u16* __restrict__ x2,
                    const float* __restrict__ g, const float* __restrict__ beta,
                    const int* __restrict__ qlen, void* __restrict__ outv, int maskOut) {
  int row = blockIdx.x;                   // B*LQ
  int b = row >> 10, q = row & 1023;
  int t = threadIdx.x;
  if (maskOut && q >= qlen[b]) {
    if (OUTF32) {
      float* o = (float*)outv + (long)row * EE;
      o[2 * t] = 0.f; o[2 * t + 1] = 0.f;
    } else {
      u16* o = (u16*)outv + (long)row * EE;
      *(unsigned int*)&o[2 * t] = 0u;
    }
    return;
  }
  __shared__ float red4[4];
  const u16* p1 = x1 + (long)row * EE;
  const u16* p2 = x2 + (long)row * EE;
  float a0 = bf2f(p1[2 * t]) + bf2f(p2[2 * t]);
  float a1 = bf2f(p1[2 * t + 1]) + bf2f(p2[2 * t + 1]);
  a0 = a0 / (1.f + __expf(-a0));
  a1 = a1 / (1.f + __expf(-a1));
  float mu = blockSum(a0 + a1, red4) * (1.f / 512.f);
  float d0 = a0 - mu, d1 = a1 - mu;
  float var = blockSum(d0 * d0 + d1 * d1, red4) * (1.f / 512.f);
  float rs = rsqrtf(var + 1e-5f);
  float r0 = d0 * rs * g[2 * t] + beta[2 * t];
  float r1 = d1 * rs * g[2 * t + 1] + beta[2 * t + 1];
  if (OUTF32) {
    float* o = (float*)outv + (long)row * EE;
    o[2 * t] = r0; o[2 * t + 1] = r1;
  } else {
    u16* o = (u16*)outv + (long)row * EE;
    o[2 * t] = f2bf(r0); o[2 * t + 1] = f2bf(r1);
  }
}

extern "C" void kernel_launch(void* const* d_in, const int* in_sizes, int n_in,
                              void* d_out, int out_size, void* d_ws, size_t ws_size,
                              hipStream_t stream) {
  const float* queries = (const float*)d_in[0];
  const float* keys    = (const float*)d_in[1];
  const int*   qlen    = (const int*)d_in[2];
  const float* cWq = (const float*)d_in[3],  *cbq = (const float*)d_in[4];
  const float* cWk = (const float*)d_in[5],  *cbk = (const float*)d_in[6];
  const float* cWv = (const float*)d_in[7],  *cbv = (const float*)d_in[8];
  const float* cWo = (const float*)d_in[9],  *cbo = (const float*)d_in[10];
  const float* sWq = (const float*)d_in[11], *sbq = (const float*)d_in[12];
  const float* sWk = (const float*)d_in[13], *sbk = (const float*)d_in[14];
  const float* sWv = (const float*)d_in[15], *sbv = (const float*)d_in[16];
  const float* sWo = (const float*)d_in[17], *sbo = (const float*)d_in[18];
  const float* Wf  = (const float*)d_in[19], *bfb = (const float*)d_in[20];
  const float* g_cross = (const float*)d_in[21], *b_cross = (const float*)d_in[22];
  const float* g_ffn   = (const float*)d_in[23], *b_ffn   = (const float*)d_in[24];
  const float* g_self  = (const float*)d_in[25], *b_self  = (const float*)d_in[26];

  float* out_q = (float*)d_out;
  float* out_w = out_q + (long)BB * SLQ * EE;

  u16* ws = (u16*)d_ws;
  u16* S     = ws;                               // 67,108,864 elems (128 MB)
  u16* Qc    = S   + (long)BB * HH * SLQ * SLK;  // [B,H,LQ,64]
  u16* Kc    = Qc  + (long)BB * HH * SLQ * HD;   // [B,H,LK,64]
  u16* Vt    = Kc  + (long)BB * HH * SLK * HD;   // [B,H,64,LK]
  u16* q0    = Vt  + (long)BB * HH * SLK * HD;
  u16* keysb = q0  + (long)BB * SLQ * EE;        // bf16 keys [B,LK,E]
  u16* attn  = keysb + (long)BB * SLK * EE;
  u16* proj  = attn + (long)BB * SLQ * EE;
  u16* q1    = proj + (long)BB * SLQ * EE;
  u16* fbuf  = q1  + (long)BB * SLQ * EE;
  u16* q2    = fbuf + (long)BB * SLQ * EE;
  u16* Wb    = q2  + (long)BB * SLQ * EE;        // 9 x 512x512 bf16 weights
  const long WSLOT = (long)EE * EE;              // 262144

  u16* bWq = Wb + 0 * WSLOT; u16* bWk = Wb + 1 * WSLOT; u16* bWv = Wb + 2 * WSLOT;
  u16* bWo = Wb + 3 * WSLOT; u16* bsWq = Wb + 4 * WSLOT; u16* bsWk = Wb + 5 * WSLOT;
  u16* bsWv = Wb + 6 * WSLOT; u16* bsWo = Wb + 7 * WSLOT; u16* bWf = Wb + 8 * WSLOT;

  dim3 blk(256);
  const int MQ = BB * SLQ;   // 4096
  const int MK = BB * SLK;   // 8192
  const int WGRID = (int)(WSLOT / 2048);  // 128

  // convert inputs to bf16
  mask_q_kernel<<<dim3((MQ * EE) / 2048), blk, 0, stream>>>(queries, q0, qlen);
  cvt_kernel<<<dim3((MK * EE) / 2048), blk, 0, stream>>>(keys, keysb);
  cvt_kernel<<<dim3(WGRID), blk, 0, stream>>>(cWq, bWq);
  cvt_kernel<<<dim3(WGRID), blk, 0, stream>>>(cWk, bWk);
  cvt_kernel<<<dim3(WGRID), blk, 0, stream>>>(cWv, bWv);
  cvt_kernel<<<dim3(WGRID), blk, 0, stream>>>(cWo, bWo);
  cvt_kernel<<<dim3(WGRID), blk, 0, stream>>>(sWq, bsWq);
  cvt_kernel<<<dim3(WGRID), blk, 0, stream>>>(sWk, bsWk);
  cvt_kernel<<<dim3(WGRID), blk, 0, stream>>>(sWv, bsWv);
  cvt_kernel<<<dim3(WGRID), blk, 0, stream>>>(sWo, bsWo);
  cvt_kernel<<<dim3(WGRID), blk, 0, stream>>>(Wf, bWf);

  // cross projections
  gemm_nt<64, 128, 1><<<dim3(EE / 128, MQ / 64, 1), blk, 0, stream>>>(
      q0, bWq, cbq, Qc, MQ, EE, EE, EE, EE, 0, 0, 0, 0, 1.0f, SLQ);
  gemm_nt<128, 128, 1><<<dim3(EE / 128, MK / 128, 1), blk, 0, stream>>>(
      keysb, bWk, cbk, Kc, MK, EE, EE, EE, EE, 0, 0, 0, 0, 1.0f, SLK);
  gemm_nt<128, 128, 2><<<dim3(EE / 128, MK / 128, 1), blk, 0, stream>>>(
      keysb, bWv, cbv, Vt, MK, EE, EE, EE, EE, 0, 0, 0, 0, 1.0f, SLK);

  // S = Q K^T * 1/8  (batched over B*H)
  gemm_nt<128, 128, 0><<<dim3(SLK / 128, SLQ / 128, BB * HH), blk, 0, stream>>>(
      Qc, Kc, nullptr, S, SLQ, SLK, HD, HD, HD, SLK,
      (long)SLQ * HD, (long)SLK * HD, (long)SLQ * SLK, 0.125f, 0);

  softmax_cross_kernel<<<dim3(BB * HH * SLQ), blk, 0, stream>>>(S, qlen);
  wmean_kernel<<<dim3((int)(((long)BB * SLQ * SLK) / 2048)), blk, 0, stream>>>(S, out_w);

  // attn = softmax(S) @ V   (stored into [B,LQ,E] with head column offset)
  gemm_nt<128, 64, 3><<<dim3(1, SLQ / 128, BB * HH), blk, 0, stream>>>(
      S, Vt, nullptr, attn, SLQ, HD, SLK, SLK, SLK, 0,
      (long)SLQ * SLK, (long)HD * SLK, 0, 1.0f, 0);

  // cross output projection
  gemm_nt<64, 128, 0><<<dim3(EE / 128, MQ / 64, 1), blk, 0, stream>>>(
      attn, bWo, cbo, proj, MQ, EE, EE, EE, EE, EE, 0, 0, 0, 1.0f, 0);

  // q1 = LN(silu(cross + q0))
  silu_ln_kernel<0><<<dim3(MQ), blk, 0, stream>>>(proj, q0, g_cross, b_cross, qlen, q1, 0);

  // f = q1 @ Wf^T + bf
  gemm_nt<64, 128, 0><<<dim3(EE / 128, MQ / 64, 1), blk, 0, stream>>>(
      q1, bWf, bfb, fbuf, MQ, EE, EE, EE, EE, EE, 0, 0, 0, 1.0f, 0);

  // q2 = mask(LN(silu(q1 + f)))
  silu_ln_kernel<0><<<dim3(MQ), blk, 0, stream>>>(q1, fbuf, g_ffn, b_ffn, qlen, q2, 1);

  // self projections (reuse Qc/Kc/Vt with L=LQ)
  gemm_nt<64, 128, 1><<<dim3(EE / 128, MQ / 64, 1), blk, 0, stream>>>(
      q2, bsWq, sbq, Qc, MQ, EE, EE, EE, EE, 0, 0, 0, 0, 1.0f, SLQ);
  gemm_nt<64, 128, 1><<<dim3(EE / 128, MQ / 64, 1), blk, 0, stream>>>(
      q2, bsWk, sbk, Kc, MQ, EE, EE, EE, EE, 0, 0, 0, 0, 1.0f, SLQ);
  gemm_nt<64, 128, 2><<<dim3(EE / 128, MQ / 64, 1), blk, 0, stream>>>(
      q2, bsWv, sbv, Vt, MQ, EE, EE, EE, EE, 0, 0, 0, 0, 1.0f, SLQ);

  // self S = Q K^T * 1/8
  gemm_nt<128, 128, 0><<<dim3(SLQ / 128, SLQ / 128, BB * HH), blk, 0, stream>>>(
      Qc, Kc, nullptr, S, SLQ, SLQ, HD, HD, HD, SLQ,
      (long)SLQ * HD, (long)SLQ * HD, (long)SLQ * SLQ, 0.125f, 0);

  softmax_self_kernel<<<dim3(BB * HH * SLQ), blk, 0, stream>>>(S, qlen);

  // self attn out
  gemm_nt<128, 64, 3><<<dim3(1, SLQ / 128, BB * HH), blk, 0, stream>>>(
      S, Vt, nullptr, attn, SLQ, HD, SLQ, SLQ, SLQ, 0,
      (long)SLQ * SLQ, (long)HD * SLQ, 0, 1.0f, 0);

  // self output projection
  gemm_nt<64, 128, 0><<<dim3(EE / 128, MQ / 64, 1), blk, 0, stream>>>(
      attn, bsWo, sbo, proj, MQ, EE, EE, EE, EE, EE, 0, 0, 0, 1.0f, 0);

  // final: out_q = mask(LN(silu(q2 + so)))  -> f32
  silu_ln_kernel<1><<<dim3(MQ), blk, 0, stream>>>(q2, proj, g_self, b_self, qlen, out_q, 1);
}

// Round 3
// 413.201 us; speedup vs baseline: 1.1807x; 1.1807x over previous
//
#include <hip/hip_runtime.h>

#define BB 4
#define SLQ 1024
#define SLK 2048
#define EE 512
#define HH 8
#define HD 64

typedef unsigned short u16;
typedef __attribute__((ext_vector_type(8))) short s16x8;
typedef __attribute__((ext_vector_type(4))) float f32x4;

__device__ __forceinline__ float bf2f(u16 u) {
  union { unsigned int i; float f; } v; v.i = ((unsigned int)u) << 16; return v.f;
}
__device__ __forceinline__ u16 f2bf(float f) {
  union { float f; unsigned int i; } v; v.f = f;
  unsigned int i = v.i;
  return (u16)((i + 0x7fffu + ((i >> 16) & 1u)) >> 16);
}

__device__ __forceinline__ void async16(const u16* g, u16* l) {
  __builtin_amdgcn_global_load_lds(
      (const __attribute__((address_space(1))) unsigned int*)g,
      (__attribute__((address_space(3))) unsigned int*)l, 16, 0, 0);
}

// NT GEMM: C[m,n] = alpha * sum_k A[m,k]*B[n,k] + bias[n]   (A,B bf16; bias f32)
// MODE 0: C + z*sCz row-major; 1: [B,H,Lsub,64]; 2: [B,H,64,Lsub]; 3: attn store
// SKIPQ 0: none; 1: b = z>>3, skip tileM >= qlen[b]; 2: b = tileM>>10 (Lsub=1024)
template<int BM, int BN, int MODE, int SKIPQ>
__global__ __launch_bounds__(256, 2)
void gemm_nt(const u16* __restrict__ A, const u16* __restrict__ Bm,
             const float* __restrict__ bias, u16* __restrict__ C,
             int M, int N, int K, int lda, int ldb, int ldc,
             long sAz, long sBz, long sCz, float alpha, int Lsub,
             const int* __restrict__ qlen)
{
  constexpr int WTM = BM / 2, WTN = BN / 2;
  constexpr int MI = WTM / 16, NI = WTN / 16;

  const int z = blockIdx.z;
  const int tileM = blockIdx.y * BM;
  const int tileN = blockIdx.x * BN;

  if (SKIPQ == 1) { if (tileM >= qlen[z >> 3]) return; }
  if (SKIPQ == 2) { int b = tileM >> 10; if ((tileM & 1023) >= qlen[b]) return; }

  __shared__ __align__(16) u16 ldsA[BM * 32];
  __shared__ __align__(16) u16 ldsB[BN * 32];

  const int t = threadIdx.x;
  const int lane = t & 63;
  const int wave = t >> 6;
  const int waveM = wave >> 1;
  const int waveN = wave & 1;
  const int lm = lane & 15;
  const int kg = lane >> 4;

  const u16* Ab = A + (long)z * sAz + (long)tileM * lda;
  const u16* Bb = Bm + (long)z * sBz + (long)tileN * ldb;

  f32x4 acc[MI][NI];
#pragma unroll
  for (int i = 0; i < MI; ++i)
#pragma unroll
    for (int j = 0; j < NI; ++j) acc[i][j] = (f32x4){0.f, 0.f, 0.f, 0.f};

  for (int kt = 0; kt < K; kt += 32) {
    __syncthreads();
#pragma unroll
    for (int i = 0; i < (BM * 4) / 256; ++i) {
      int c = i * 256 + t;
      async16(Ab + (long)(c >> 2) * lda + kt + (c & 3) * 8, ldsA + (c - lane) * 8);
    }
#pragma unroll
    for (int i = 0; i < (BN * 4) / 256; ++i) {
      int c = i * 256 + t;
      async16(Bb + (long)(c >> 2) * ldb + kt + (c & 3) * 8, ldsB + (c - lane) * 8);
    }
    __syncthreads();

    s16x8 aF[MI], bF[NI];
#pragma unroll
    for (int i = 0; i < MI; ++i)
      aF[i] = *(const s16x8*)&ldsA[(waveM * WTM + i * 16 + lm) * 32 + kg * 8];
#pragma unroll
    for (int j = 0; j < NI; ++j)
      bF[j] = *(const s16x8*)&ldsB[(waveN * WTN + j * 16 + lm) * 32 + kg * 8];
#pragma unroll
    for (int i = 0; i < MI; ++i)
#pragma unroll
      for (int j = 0; j < NI; ++j)
        acc[i][j] = __builtin_amdgcn_mfma_f32_16x16x32_bf16(aF[i], bF[j], acc[i][j], 0, 0, 0);
  }

#pragma unroll
  for (int j = 0; j < NI; ++j) {
    int n = tileN + waveN * WTN + j * 16 + lm;
    float bv = bias ? bias[n] : 0.0f;
#pragma unroll
    for (int i = 0; i < MI; ++i) {
#pragma unroll
      for (int r = 0; r < 4; ++r) {
        int m = tileM + waveM * WTM + i * 16 + kg * 4 + r;
        float v = acc[i][j][r] * alpha + bv;
        if (MODE == 0) {
          C[(long)z * sCz + (long)m * ldc + n] = f2bf(v);
        } else if (MODE == 1) {
          int b = m / Lsub, l = m - b * Lsub;
          int h = n >> 6, d = n & 63;
          C[(((long)(b * HH + h) * Lsub + l) << 6) + d] = f2bf(v);
        } else if (MODE == 2) {
          int b = m / Lsub, l = m - b * Lsub;
          int h = n >> 6, d = n & 63;
          C[((long)(b * HH + h) * HD + d) * Lsub + l] = f2bf(v);
        } else {
          int b = z >> 3, h = z & 7;
          C[(long)b * SLQ * EE + (long)m * EE + h * HD + n] = f2bf(v);
        }
      }
    }
  }
}

// ---------------- self-attention flash (single pass, online softmax) --------
#define TQ 128
#define TK 128

__global__ __launch_bounds__(256, 2)
void self_flash_kernel(const u16* __restrict__ Qc, const u16* __restrict__ Kc,
                       const u16* __restrict__ Vt, u16* __restrict__ attn,
                       const int* __restrict__ qlen)
{
  const int qt = blockIdx.x;           // 8 q-tiles
  const int bh = blockIdx.y;           // b*8+h
  const int b = bh >> 3, h = bh & 7;
  const int kmax = qlen[b];
  if (qt * TQ >= kmax) return;         // output rows masked downstream

  __shared__ __align__(16) u16 Kt[TK * 72];       // [k][d], stride 72
  __shared__ __align__(16) u16 Vl[64 * 136];      // [d][k], stride 136
  __shared__ __align__(16) u16 Pl[4 * 32 * 136];  // per-wave P [32][136]

  const int t = threadIdx.x;
  const int lane = t & 63;
  const int w = t >> 6;
  const int col = lane & 15;
  const int quad = lane >> 4;

  const u16* Qb = Qc + (long)bh * SLQ * HD;
  const u16* Kb = Kc + (long)bh * SLQ * HD;
  const u16* Vb = Vt + (long)bh * HD * SLQ;

  s16x8 aQ[2][2];
#pragma unroll
  for (int i = 0; i < 2; ++i)
#pragma unroll
    for (int kk = 0; kk < 2; ++kk)
      aQ[i][kk] = *(const s16x8*)(Qb + (long)(qt * TQ + w * 32 + i * 16 + col) * HD +
                                  kk * 32 + quad * 8);

  f32x4 s[2][8], O[2][4];
  float mrow[2][4], lrow[2][4];
#pragma unroll
  for (int i = 0; i < 2; ++i)
#pragma unroll
    for (int n = 0; n < 4; ++n) O[i][n] = (f32x4){0.f, 0.f, 0.f, 0.f};
#pragma unroll
  for (int i = 0; i < 2; ++i)
#pragma unroll
    for (int r = 0; r < 4; ++r) { mrow[i][r] = -1e30f; lrow[i][r] = 0.f; }

  u16* Pw = Pl + w * 32 * 136;
  const int nkt = (kmax + TK - 1) / TK;

  for (int kt = 0; kt < nkt; ++kt) {
    const int k0 = kt * TK;
    __syncthreads();
    for (int c = t; c < 1024; c += 256) {          // K-tile 16 KB
      int r = c >> 3, c8 = c & 7;
      *(uint4*)&Kt[r * 72 + c8 * 8] = *(const uint4*)(Kb + (long)(k0 + r) * HD + c8 * 8);
    }
    for (int c = t; c < 1024; c += 256) {          // V-tile 16 KB
      int d = c >> 4, c16 = c & 15;
      *(uint4*)&Vl[d * 136 + c16 * 8] = *(const uint4*)(Vb + (long)d * SLQ + k0 + c16 * 8);
    }
    __syncthreads();

#pragma unroll
    for (int i = 0; i < 2; ++i)
#pragma unroll
      for (int j = 0; j < 8; ++j) s[i][j] = (f32x4){0.f, 0.f, 0.f, 0.f};
#pragma unroll
    for (int j = 0; j < 8; ++j) {
#pragma unroll
      for (int kk = 0; kk < 2; ++kk) {
        s16x8 bK = *(const s16x8*)&Kt[(j * 16 + col) * 72 + kk * 32 + quad * 8];
        s[0][j] = __builtin_amdgcn_mfma_f32_16x16x32_bf16(aQ[0][kk], bK, s[0][j], 0, 0, 0);
        s[1][j] = __builtin_amdgcn_mfma_f32_16x16x32_bf16(aQ[1][kk], bK, s[1][j], 0, 0, 0);
      }
    }
    // scale + key mask
#pragma unroll
    for (int j = 0; j < 8; ++j) {
      bool ok = (k0 + j * 16 + col) < kmax;
#pragma unroll
      for (int i = 0; i < 2; ++i)
#pragma unroll
        for (int r = 0; r < 4; ++r)
          s[i][j][r] = ok ? s[i][j][r] * 0.125f : -1e30f;
    }
    // online softmax per q-row (row lives in the 16 lanes of a quad)
#pragma unroll
    for (int i = 0; i < 2; ++i) {
#pragma unroll
      for (int r = 0; r < 4; ++r) {
        float tm = s[i][0][r];
#pragma unroll
        for (int j = 1; j < 8; ++j) tm = fmaxf(tm, s[i][j][r]);
#pragma unroll
        for (int o = 1; o <= 8; o <<= 1) tm = fmaxf(tm, __shfl_xor(tm, o));
        float mnew = fmaxf(mrow[i][r], tm);
        float alpha = __expf(mrow[i][r] - mnew);
        mrow[i][r] = mnew;
        float ps = 0.f;
#pragma unroll
        for (int j = 0; j < 8; ++j) {
          float p = __expf(s[i][j][r] - mnew);
          s[i][j][r] = p;
          ps += p;
        }
#pragma unroll
        for (int o = 1; o <= 8; o <<= 1) ps += __shfl_xor(ps, o);
        lrow[i][r] = lrow[i][r] * alpha + ps;
#pragma unroll
        for (int n = 0; n < 4; ++n) O[i][n][r] *= alpha;
      }
    }
    // P -> LDS (C-layout write, A-layout read)
#pragma unroll
    for (int i = 0; i < 2; ++i)
#pragma unroll
      for (int j = 0; j < 8; ++j)
#pragma unroll
        for (int r = 0; r < 4; ++r)
          Pw[(i * 16 + quad * 4 + r) * 136 + j * 16 + col] = f2bf(s[i][j][r]);
    // O += P V
#pragma unroll
    for (int kk = 0; kk < 4; ++kk) {
      s16x8 aP0 = *(const s16x8*)&Pw[col * 136 + kk * 32 + quad * 8];
      s16x8 aP1 = *(const s16x8*)&Pw[(16 + col) * 136 + kk * 32 + quad * 8];
#pragma unroll
      for (int n = 0; n < 4; ++n) {
        s16x8 bV = *(const s16x8*)&Vl[(n * 16 + col) * 136 + kk * 32 + quad * 8];
        O[0][n] = __builtin_amdgcn_mfma_f32_16x16x32_bf16(aP0, bV, O[0][n], 0, 0, 0);
        O[1][n] = __builtin_amdgcn_mfma_f32_16x16x32_bf16(aP1, bV, O[1][n], 0, 0, 0);
      }
    }
  }

#pragma unroll
  for (int i = 0; i < 2; ++i) {
#pragma unroll
    for (int r = 0; r < 4; ++r) {
      float inv = 1.0f / lrow[i][r];
      int q = qt * TQ + w * 32 + i * 16 + quad * 4 + r;
      u16* orow = attn + ((long)b * SLQ + q) * EE + h * HD;
#pragma unroll
      for (int n = 0; n < 4; ++n) orow[n * 16 + col] = f2bf(O[i][n][r] * inv);
    }
  }
}

// f32 -> bf16 conversion, 8 elems/thread
__global__ __launch_bounds__(256)
void cvt_kernel(const float* __restrict__ in, u16* __restrict__ out) {
  long base = ((long)blockIdx.x * 256 + threadIdx.x) * 8;
  float4 a = *(const float4*)&in[base];
  float4 b = *(const float4*)&in[base + 4];
  s16x8 o;
  o[0] = (short)f2bf(a.x); o[1] = (short)f2bf(a.y);
  o[2] = (short)f2bf(a.z); o[3] = (short)f2bf(a.w);
  o[4] = (short)f2bf(b.x); o[5] = (short)f2bf(b.y);
  o[6] = (short)f2bf(b.z); o[7] = (short)f2bf(b.w);
  *(s16x8*)&out[base] = o;
}

// all 9 weight matrices in one launch (128 blocks per 512x512 matrix)
__global__ __launch_bounds__(256)
void wcvt_kernel(const float* s0, const float* s1, const float* s2,
                 const float* s3, const float* s4, const float* s5,
                 const float* s6, const float* s7, const float* s8,
                 u16* __restrict__ dst) {
  int mat = blockIdx.x >> 7, part = blockIdx.x & 127;
  const float* srcs[9] = {s0, s1, s2, s3, s4, s5, s6, s7, s8};
  const float* src = srcs[mat];
  long off = (long)part * 2048 + threadIdx.x * 8;
  float4 a = *(const float4*)&src[off];
  float4 b = *(const float4*)&src[off + 4];
  s16x8 o;
  o[0] = (short)f2bf(a.x); o[1] = (short)f2bf(a.y);
  o[2] = (short)f2bf(a.z); o[3] = (short)f2bf(a.w);
  o[4] = (short)f2bf(b.x); o[5] = (short)f2bf(b.y);
  o[6] = (short)f2bf(b.z); o[7] = (short)f2bf(b.w);
  *(s16x8*)&dst[(long)mat * EE * EE + off] = o;
}

// queries f32 -> masked bf16 q0
__global__ __launch_bounds__(256)
void mask_q_kernel(const float* __restrict__ in, u16* __restrict__ out,
                   const int* __restrict__ qlen) {
  long base = ((long)blockIdx.x * 256 + threadIdx.x) * 8;
  int row = (int)(base >> 9);
  int b = row >> 10, q = row & 1023;
  s16x8 o = (s16x8){0, 0, 0, 0, 0, 0, 0, 0};
  if (q < qlen[b]) {
    float4 a = *(const float4*)&in[base];
    float4 c = *(const float4*)&in[base + 4];
    o[0] = (short)f2bf(a.x); o[1] = (short)f2bf(a.y);
    o[2] = (short)f2bf(a.z); o[3] = (short)f2bf(a.w);
    o[4] = (short)f2bf(c.x); o[5] = (short)f2bf(c.y);
    o[6] = (short)f2bf(c.z); o[7] = (short)f2bf(c.w);
  }
  *(s16x8*)&out[base] = o;
}

__device__ __forceinline__ float blockSum(float v, float* red4) {
#pragma unroll
  for (int o = 32; o; o >>= 1) v += __shfl_xor(v, o);
  if ((threadIdx.x & 63) == 0) red4[threadIdx.x >> 6] = v;
  __syncthreads();
  v = red4[0] + red4[1] + red4[2] + red4[3];
  __syncthreads();
  return v;
}
__device__ __forceinline__ float blockMax(float v, float* red4) {
#pragma unroll
  for (int o = 32; o; o >>= 1) v = fmaxf(v, __shfl_xor(v, o));
  if ((threadIdx.x & 63) == 0) red4[threadIdx.x >> 6] = v;
  __syncthreads();
  v = fmaxf(fmaxf(red4[0], red4[1]), fmaxf(red4[2], red4[3]));
  __syncthreads();
  return v;
}

// fused cross softmax (8 heads) + head-mean output; invalid q rows: only zero out_w
__global__ __launch_bounds__(256)
void softmax_wmean_cross(u16* __restrict__ S, float* __restrict__ outw,
                         const int* __restrict__ qlen) {
  int row = blockIdx.x;               // b*1024 + q
  int b = row >> 10, q = row & 1023;
  int t = threadIdx.x;
  float* wr = outw + (long)row * SLK + t * 8;
  if (q >= qlen[b]) {
    float4 z = {0.f, 0.f, 0.f, 0.f};
    *(float4*)wr = z; *(float4*)(wr + 4) = z;
    return;
  }
  __shared__ float red4[4];
  float acc[8] = {0, 0, 0, 0, 0, 0, 0, 0};
  for (int h = 0; h < HH; ++h) {
    u16* p = S + ((long)((b * HH + h) * SLQ + q)) * SLK + t * 8;
    s16x8 v = *(const s16x8*)p;
    float x[8]; float m = -1e30f;
#pragma unroll
    for (int j = 0; j < 8; ++j) { x[j] = bf2f((u16)v[j]); m = fmaxf(m, x[j]); }
    m = blockMax(m, red4);
    float ssum = 0.f;
#pragma unroll
    for (int j = 0; j < 8; ++j) { x[j] = __expf(x[j] - m); ssum += x[j]; }
    ssum = blockSum(ssum, red4);
    float r = 1.0f / ssum;
#pragma unroll
    for (int j = 0; j < 8; ++j) {
      float pj = x[j] * r;
      v[j] = (short)f2bf(pj);
      acc[j] += pj;
    }
    *(s16x8*)p = v;
  }
#pragma unroll
  for (int j = 0; j < 8; ++j) wr[j] = acc[j] * 0.125f;
}

// out = LN(silu(x1+x2))*g + beta; mode 0: all rows; 1: zero invalid; 2: skip invalid
template<int OUTF32>
__global__ __launch_bounds__(256)
void silu_ln_kernel(const u16* __restrict__ x1, const u16* __restrict__ x2,
                    const float* __restrict__ g, const float* __restrict__ beta,
                    const int* __restrict__ qlen, void* __restrict__ outv, int mode) {
  int row = blockIdx.x;
  int b = row >> 10, q = row & 1023;
  int t = threadIdx.x;
  if (mode && q >= qlen[b]) {
    if (mode == 1) {
      if (OUTF32) {
        float* o = (float*)outv + (long)row * EE;
        o[2 * t] = 0.f; o[2 * t + 1] = 0.f;
      } else {
        u16* o = (u16*)outv + (long)row * EE;
        *(unsigned int*)&o[2 * t] = 0u;
      }
    }
    return;
  }
  __shared__ float red4[4];
  const u16* p1 = x1 + (long)row * EE;
  const u16* p2 = x2 + (long)row * EE;
  float a0 = bf2f(p1[2 * t]) + bf2f(p2[2 * t]);
  float a1 = bf2f(p1[2 * t + 1]) + bf2f(p2[2 * t + 1]);
  a0 = a0 / (1.f + __expf(-a0));
  a1 = a1 / (1.f + __expf(-a1));
  float mu = blockSum(a0 + a1, red4) * (1.f / 512.f);
  float d0 = a0 - mu, d1 = a1 - mu;
  float var = blockSum(d0 * d0 + d1 * d1, red4) * (1.f / 512.f);
  float rs = rsqrtf(var + 1e-5f);
  float r0 = d0 * rs * g[2 * t] + beta[2 * t];
  float r1 = d1 * rs * g[2 * t + 1] + beta[2 * t + 1];
  if (OUTF32) {
    float* o = (float*)outv + (long)row * EE;
    o[2 * t] = r0; o[2 * t + 1] = r1;
  } else {
    u16* o = (u16*)outv + (long)row * EE;
    o[2 * t] = f2bf(r0); o[2 * t + 1] = f2bf(r1);
  }
}

extern "C" void kernel_launch(void* const* d_in, const int* in_sizes, int n_in,
                              void* d_out, int out_size, void* d_ws, size_t ws_size,
                              hipStream_t stream) {
  const float* queries = (const float*)d_in[0];
  const float* keys    = (const float*)d_in[1];
  const int*   qlen    = (const int*)d_in[2];
  const float* cWq = (const float*)d_in[3],  *cbq = (const float*)d_in[4];
  const float* cWk = (const float*)d_in[5],  *cbk = (const float*)d_in[6];
  const float* cWv = (const float*)d_in[7],  *cbv = (const float*)d_in[8];
  const float* cWo = (const float*)d_in[9],  *cbo = (const float*)d_in[10];
  const float* sWq = (const float*)d_in[11], *sbq = (const float*)d_in[12];
  const float* sWk = (const float*)d_in[13], *sbk = (const float*)d_in[14];
  const float* sWv = (const float*)d_in[15], *sbv = (const float*)d_in[16];
  const float* sWo = (const float*)d_in[17], *sbo = (const float*)d_in[18];
  const float* Wf  = (const float*)d_in[19], *bfb = (const float*)d_in[20];
  const float* g_cross = (const float*)d_in[21], *b_cross = (const float*)d_in[22];
  const float* g_ffn   = (const float*)d_in[23], *b_ffn   = (const float*)d_in[24];
  const float* g_self  = (const float*)d_in[25], *b_self  = (const float*)d_in[26];

  float* out_q = (float*)d_out;
  float* out_w = out_q + (long)BB * SLQ * EE;

  u16* ws = (u16*)d_ws;
  u16* S     = ws;
  u16* Qc    = S   + (long)BB * HH * SLQ * SLK;
  u16* Kc    = Qc  + (long)BB * HH * SLQ * HD;
  u16* Vt    = Kc  + (long)BB * HH * SLK * HD;
  u16* q0    = Vt  + (long)BB * HH * SLK * HD;
  u16* keysb = q0  + (long)BB * SLQ * EE;
  u16* attn  = keysb + (long)BB * SLK * EE;
  u16* proj  = attn + (long)BB * SLQ * EE;
  u16* q1    = proj + (long)BB * SLQ * EE;
  u16* fbuf  = q1  + (long)BB * SLQ * EE;
  u16* q2    = fbuf + (long)BB * SLQ * EE;
  u16* Wb    = q2  + (long)BB * SLQ * EE;
  const long WSLOT = (long)EE * EE;

  u16* bWq = Wb + 0 * WSLOT; u16* bWk = Wb + 1 * WSLOT; u16* bWv = Wb + 2 * WSLOT;
  u16* bWo = Wb + 3 * WSLOT; u16* bsWq = Wb + 4 * WSLOT; u16* bsWk = Wb + 5 * WSLOT;
  u16* bsWv = Wb + 6 * WSLOT; u16* bsWo = Wb + 7 * WSLOT; u16* bWf = Wb + 8 * WSLOT;

  dim3 blk(256);
  const int MQ = BB * SLQ;   // 4096
  const int MK = BB * SLK;   // 8192

  mask_q_kernel<<<dim3((MQ * EE) / 2048), blk, 0, stream>>>(queries, q0, qlen);
  cvt_kernel<<<dim3((MK * EE) / 2048), blk, 0, stream>>>(keys, keysb);
  wcvt_kernel<<<dim3(9 * 128), blk, 0, stream>>>(cWq, cWk, cWv, cWo, sWq, sWk, sWv, sWo, Wf, Wb);

  // cross projections
  gemm_nt<64, 128, 1, 2><<<dim3(EE / 128, MQ / 64, 1), blk, 0, stream>>>(
      q0, bWq, cbq, Qc, MQ, EE, EE, EE, EE, 0, 0, 0, 0, 1.0f, SLQ, qlen);
  gemm_nt<128, 128, 1, 0><<<dim3(EE / 128, MK / 128, 1), blk, 0, stream>>>(
      keysb, bWk, cbk, Kc, MK, EE, EE, EE, EE, 0, 0, 0, 0, 1.0f, SLK, qlen);
  gemm_nt<128, 128, 2, 0><<<dim3(EE / 128, MK / 128, 1), blk, 0, stream>>>(
      keysb, bWv, cbv, Vt, MK, EE, EE, EE, EE, 0, 0, 0, 0, 1.0f, SLK, qlen);

  // S = Q K^T * 1/8  (skip invalid q tiles)
  gemm_nt<128, 128, 0, 1><<<dim3(SLK / 128, SLQ / 128, BB * HH), blk, 0, stream>>>(
      Qc, Kc, nullptr, S, SLQ, SLK, HD, HD, HD, SLK,
      (long)SLQ * HD, (long)SLK * HD, (long)SLQ * SLK, 0.125f, 0, qlen);

  softmax_wmean_cross<<<dim3(BB * SLQ), blk, 0, stream>>>(S, out_w, qlen);

  gemm_nt<128, 64, 3, 1><<<dim3(1, SLQ / 128, BB * HH), blk, 0, stream>>>(
      S, Vt, nullptr, attn, SLQ, HD, SLK, SLK, SLK, 0,
      (long)SLQ * SLK, (long)HD * SLK, 0, 1.0f, 0, qlen);

  gemm_nt<64, 128, 0, 2><<<dim3(EE / 128, MQ / 64, 1), blk, 0, stream>>>(
      attn, bWo, cbo, proj, MQ, EE, EE, EE, EE, EE, 0, 0, 0, 1.0f, SLQ, qlen);

  silu_ln_kernel<0><<<dim3(MQ), blk, 0, stream>>>(proj, q0, g_cross, b_cross, qlen, q1, 2);

  gemm_nt<64, 128, 0, 2><<<dim3(EE / 128, MQ / 64, 1), blk, 0, stream>>>(
      q1, bWf, bfb, fbuf, MQ, EE, EE, EE, EE, EE, 0, 0, 0, 1.0f, SLQ, qlen);

  silu_ln_kernel<0><<<dim3(MQ), blk, 0, stream>>>(q1, fbuf, g_ffn, b_ffn, qlen, q2, 1);

  // self projections
  gemm_nt<64, 128, 1, 2><<<dim3(EE / 128, MQ / 64, 1), blk, 0, stream>>>(
      q2, bsWq, sbq, Qc, MQ, EE, EE, EE, EE, 0, 0, 0, 0, 1.0f, SLQ, qlen);
  gemm_nt<64, 128, 1, 2><<<dim3(EE / 128, MQ / 64, 1), blk, 0, stream>>>(
      q2, bsWk, sbk, Kc, MQ, EE, EE, EE, EE, 0, 0, 0, 0, 1.0f, SLQ, qlen);
  gemm_nt<64, 128, 2, 2><<<dim3(EE / 128, MQ / 64, 1), blk, 0, stream>>>(
      q2, bsWv, sbv, Vt, MQ, EE, EE, EE, EE, 0, 0, 0, 0, 1.0f, SLQ, qlen);

  // fused self attention (QK^T + online softmax + PV)
  self_flash_kernel<<<dim3(SLQ / TQ, BB * HH), blk, 0, stream>>>(Qc, Kc, Vt, attn, qlen);

  gemm_nt<64, 128, 0, 2><<<dim3(EE / 128, MQ / 64, 1), blk, 0, stream>>>(
      attn, bsWo, sbo, proj, MQ, EE, EE, EE, EE, EE, 0, 0, 0, 1.0f, SLQ, qlen);

  silu_ln_kernel<1><<<dim3(MQ), blk, 0, stream>>>(q2, proj, g_self, b_self, qlen, out_q, 1);
}

// Round 4
// 385.529 us; speedup vs baseline: 1.2654x; 1.0718x over previous
//
#include <hip/hip_runtime.h>

#define BB 4
#define SLQ 1024
#define SLK 2048
#define EE 512
#define HH 8
#define HD 64

typedef unsigned short u16;
typedef __attribute__((ext_vector_type(8))) short s16x8;
typedef __attribute__((ext_vector_type(4))) float f32x4;

__device__ __forceinline__ float bf2f(u16 u) {
  union { unsigned int i; float f; } v; v.i = ((unsigned int)u) << 16; return v.f;
}
__device__ __forceinline__ u16 f2bf(float f) {
  union { float f; unsigned int i; } v; v.f = f;
  unsigned int i = v.i;
  return (u16)((i + 0x7fffu + ((i >> 16) & 1u)) >> 16);
}

__device__ __forceinline__ void async16(const u16* g, u16* l) {
  __builtin_amdgcn_global_load_lds(
      (const __attribute__((address_space(1))) unsigned int*)g,
      (__attribute__((address_space(3))) unsigned int*)l, 16, 0, 0);
}

// NT GEMM: C[m,n] = alpha * sum_k A[m,k]*B[n,k] + bias[n]   (A,B bf16; bias f32)
// MODE 0: C + z*sCz row-major; 1: [B,H,Lsub,64]; 2: [B,H,64,Lsub]; 3: attn store
// MODE 4: split-K PV partial: gridDim.x = K-split index, koff = x*Lsub, tileN=0,
//         bf16 partial store C[((z*SLQ+m)*4 + x)*64 + n]
// SKIPQ 0: none; 1: b = z>>3, skip tileM >= qlen[b]; 2: b = tileM>>10 (Lsub=1024)
template<int BM, int BN, int MODE, int SKIPQ>
__global__ __launch_bounds__(256, 2)
void gemm_nt(const u16* __restrict__ A, const u16* __restrict__ Bm,
             const float* __restrict__ bias, u16* __restrict__ C,
             int M, int N, int K, int lda, int ldb, int ldc,
             long sAz, long sBz, long sCz, float alpha, int Lsub,
             const int* __restrict__ qlen)
{
  constexpr int WTM = BM / 2, WTN = BN / 2;
  constexpr int MI = WTM / 16, NI = WTN / 16;

  const int z = blockIdx.z;
  const int tileM = blockIdx.y * BM;
  const int tileN = (MODE == 4) ? 0 : blockIdx.x * BN;
  const long koff = (MODE == 4) ? (long)blockIdx.x * Lsub : 0;

  if (SKIPQ == 1) { if (tileM >= qlen[z >> 3]) return; }
  if (SKIPQ == 2) { int b = tileM >> 10; if ((tileM & 1023) >= qlen[b]) return; }

  __shared__ __align__(16) u16 ldsA[BM * 32];
  __shared__ __align__(16) u16 ldsB[BN * 32];

  const int t = threadIdx.x;
  const int lane = t & 63;
  const int wave = t >> 6;
  const int waveM = wave >> 1;
  const int waveN = wave & 1;
  const int lm = lane & 15;
  const int kg = lane >> 4;

  const u16* Ab = A + (long)z * sAz + (long)tileM * lda + koff;
  const u16* Bb = Bm + (long)z * sBz + (long)tileN * ldb + koff;

  f32x4 acc[MI][NI];
#pragma unroll
  for (int i = 0; i < MI; ++i)
#pragma unroll
    for (int j = 0; j < NI; ++j) acc[i][j] = (f32x4){0.f, 0.f, 0.f, 0.f};

  for (int kt = 0; kt < K; kt += 32) {
    __syncthreads();
#pragma unroll
    for (int i = 0; i < (BM * 4) / 256; ++i) {
      int c = i * 256 + t;
      async16(Ab + (long)(c >> 2) * lda + kt + (c & 3) * 8, ldsA + (c - lane) * 8);
    }
#pragma unroll
    for (int i = 0; i < (BN * 4) / 256; ++i) {
      int c = i * 256 + t;
      async16(Bb + (long)(c >> 2) * ldb + kt + (c & 3) * 8, ldsB + (c - lane) * 8);
    }
    __syncthreads();

    s16x8 aF[MI], bF[NI];
#pragma unroll
    for (int i = 0; i < MI; ++i)
      aF[i] = *(const s16x8*)&ldsA[(waveM * WTM + i * 16 + lm) * 32 + kg * 8];
#pragma unroll
    for (int j = 0; j < NI; ++j)
      bF[j] = *(const s16x8*)&ldsB[(waveN * WTN + j * 16 + lm) * 32 + kg * 8];
#pragma unroll
    for (int i = 0; i < MI; ++i)
#pragma unroll
      for (int j = 0; j < NI; ++j)
        acc[i][j] = __builtin_amdgcn_mfma_f32_16x16x32_bf16(aF[i], bF[j], acc[i][j], 0, 0, 0);
  }

#pragma unroll
  for (int j = 0; j < NI; ++j) {
    int n = tileN + waveN * WTN + j * 16 + lm;
    float bv = bias ? bias[n] : 0.0f;
#pragma unroll
    for (int i = 0; i < MI; ++i) {
#pragma unroll
      for (int r = 0; r < 4; ++r) {
        int m = tileM + waveM * WTM + i * 16 + kg * 4 + r;
        float v = acc[i][j][r] * alpha + bv;
        if (MODE == 0) {
          C[(long)z * sCz + (long)m * ldc + n] = f2bf(v);
        } else if (MODE == 1) {
          int b = m / Lsub, l = m - b * Lsub;
          int h = n >> 6, d = n & 63;
          C[(((long)(b * HH + h) * Lsub + l) << 6) + d] = f2bf(v);
        } else if (MODE == 2) {
          int b = m / Lsub, l = m - b * Lsub;
          int h = n >> 6, d = n & 63;
          C[((long)(b * HH + h) * HD + d) * Lsub + l] = f2bf(v);
        } else if (MODE == 3) {
          int b = z >> 3, h = z & 7;
          C[(long)b * SLQ * EE + (long)m * EE + h * HD + n] = f2bf(v);
        } else {
          C[(((long)z * SLQ + m) * 4 + blockIdx.x) * 64 + n] = f2bf(v);
        }
      }
    }
  }
}

// ------------- self-attention: chunked flash (one K-chunk per block) --------
__global__ __launch_bounds__(256, 3)
void self_flash_chunk(const u16* __restrict__ Qc, const u16* __restrict__ Kc,
                      const u16* __restrict__ Vt, float* __restrict__ Opart,
                      float* __restrict__ ml, const int* __restrict__ qlen)
{
  const int qt = blockIdx.x;           // 16 q-tiles of 64
  const int bh = blockIdx.y;           // 32
  const int ck = blockIdx.z;           // 8 chunks of 128 keys
  const int b = bh >> 3;
  const int kmax = qlen[b];
  const int k0 = ck * 128;
  if (qt * 64 >= kmax || k0 >= kmax) return;

  __shared__ __align__(16) u16 Kt[128 * 72];
  __shared__ __align__(16) u16 Vl[64 * 136];
  __shared__ __align__(16) u16 Pl[4 * 16 * 136];

  const int t = threadIdx.x, lane = t & 63, w = t >> 6;
  const int col = lane & 15, quad = lane >> 4;

  const u16* Qb = Qc + (long)bh * SLQ * HD;
  const u16* Kb = Kc + (long)bh * SLQ * HD;
  const u16* Vb = Vt + (long)bh * HD * SLQ;

  for (int c = t; c < 1024; c += 256) {
    int r = c >> 3, c8 = c & 7;
    *(uint4*)&Kt[r * 72 + c8 * 8] = *(const uint4*)(Kb + (long)(k0 + r) * HD + c8 * 8);
  }
  for (int c = t; c < 1024; c += 256) {
    int d = c >> 4, c16 = c & 15;
    *(uint4*)&Vl[d * 136 + c16 * 8] = *(const uint4*)(Vb + (long)d * SLQ + k0 + c16 * 8);
  }
  s16x8 aQ[2];
#pragma unroll
  for (int kk = 0; kk < 2; ++kk)
    aQ[kk] = *(const s16x8*)(Qb + (long)(qt * 64 + w * 16 + col) * HD + kk * 32 + quad * 8);
  __syncthreads();

  f32x4 s[8];
#pragma unroll
  for (int j = 0; j < 8; ++j) s[j] = (f32x4){0.f, 0.f, 0.f, 0.f};
#pragma unroll
  for (int j = 0; j < 8; ++j)
#pragma unroll
    for (int kk = 0; kk < 2; ++kk) {
      s16x8 bK = *(const s16x8*)&Kt[(j * 16 + col) * 72 + kk * 32 + quad * 8];
      s[j] = __builtin_amdgcn_mfma_f32_16x16x32_bf16(aQ[kk], bK, s[j], 0, 0, 0);
    }
#pragma unroll
  for (int j = 0; j < 8; ++j) {
    bool ok = (k0 + j * 16 + col) < kmax;
#pragma unroll
    for (int r = 0; r < 4; ++r)
      s[j][r] = ok ? s[j][r] * 0.125f : -1e30f;
  }
  float mr[4], lr[4];
#pragma unroll
  for (int r = 0; r < 4; ++r) {
    float tm = s[0][r];
#pragma unroll
    for (int j = 1; j < 8; ++j) tm = fmaxf(tm, s[j][r]);
#pragma unroll
    for (int o = 1; o <= 8; o <<= 1) tm = fmaxf(tm, __shfl_xor(tm, o));
    mr[r] = tm;
    float ps = 0.f;
#pragma unroll
    for (int j = 0; j < 8; ++j) {
      float p = __expf(s[j][r] - tm);
      s[j][r] = p;
      ps += p;
    }
#pragma unroll
    for (int o = 1; o <= 8; o <<= 1) ps += __shfl_xor(ps, o);
    lr[r] = ps;
  }
  u16* Pw = Pl + w * 16 * 136;
#pragma unroll
  for (int j = 0; j < 8; ++j)
#pragma unroll
    for (int r = 0; r < 4; ++r)
      Pw[(quad * 4 + r) * 136 + j * 16 + col] = f2bf(s[j][r]);

  f32x4 O[4];
#pragma unroll
  for (int n = 0; n < 4; ++n) O[n] = (f32x4){0.f, 0.f, 0.f, 0.f};
#pragma unroll
  for (int kk = 0; kk < 4; ++kk) {
    s16x8 aP = *(const s16x8*)&Pw[col * 136 + kk * 32 + quad * 8];
#pragma unroll
    for (int n = 0; n < 4; ++n) {
      s16x8 bV = *(const s16x8*)&Vl[(n * 16 + col) * 136 + kk * 32 + quad * 8];
      O[n] = __builtin_amdgcn_mfma_f32_16x16x32_bf16(aP, bV, O[n], 0, 0, 0);
    }
  }
#pragma unroll
  for (int r = 0; r < 4; ++r) {
    int q = qt * 64 + w * 16 + quad * 4 + r;
    long gq = (long)bh * SLQ + q;
#pragma unroll
    for (int n = 0; n < 4; ++n)
      Opart[(gq * 8 + ck) * 64 + n * 16 + col] = O[n][r];
    if (col == 0) {
      ml[(gq * 8 + ck) * 2] = mr[r];
      ml[(gq * 8 + ck) * 2 + 1] = lr[r];
    }
  }
}

// merge <=8 chunk partials per row (flash-2 rescale), write attn bf16
__global__ __launch_bounds__(256)
void self_combine(const float* __restrict__ Opart, const float* __restrict__ ml,
                  u16* __restrict__ attn, const int* __restrict__ qlen)
{
  int gr = blockIdx.x * 16 + (threadIdx.x >> 4);
  int bh = gr >> 10, q = gr & 1023;
  int b = bh >> 3, h = bh & 7;
  int kmax = qlen[b];
  if (q >= kmax) return;
  int NC = (kmax + 127) >> 7;
  int d = (threadIdx.x & 15) * 4;
  long base = (long)gr * 8;
  float M = -1e30f;
  for (int c = 0; c < NC; ++c) M = fmaxf(M, ml[(base + c) * 2]);
  float L = 0.f;
  float ax = 0.f, ay = 0.f, az = 0.f, aw = 0.f;
  for (int c = 0; c < NC; ++c) {
    float wgt = __expf(ml[(base + c) * 2] - M);
    L += ml[(base + c) * 2 + 1] * wgt;
    float4 o = *(const float4*)&Opart[(base + c) * 64 + d];
    ax += o.x * wgt; ay += o.y * wgt; az += o.z * wgt; aw += o.w * wgt;
  }
  float inv = 1.0f / L;
  u16* orow = attn + ((long)b * SLQ + q) * EE + h * HD + d;
  orow[0] = f2bf(ax * inv); orow[1] = f2bf(ay * inv);
  orow[2] = f2bf(az * inv); orow[3] = f2bf(aw * inv);
}

// sum 4 split-K bf16 partials -> attn
__global__ __launch_bounds__(256)
void pv_combine(const u16* __restrict__ Cp, u16* __restrict__ attn,
                const int* __restrict__ qlen)
{
  int gr = blockIdx.x * 16 + (threadIdx.x >> 4);
  int bh = gr >> 10, q = gr & 1023;
  int b = bh >> 3, h = bh & 7;
  if (q >= qlen[b]) return;
  int d = (threadIdx.x & 15) * 4;
  float a0 = 0.f, a1 = 0.f, a2 = 0.f, a3 = 0.f;
  for (int ks = 0; ks < 4; ++ks) {
    const u16* p = Cp + ((long)gr * 4 + ks) * 64 + d;
    a0 += bf2f(p[0]); a1 += bf2f(p[1]); a2 += bf2f(p[2]); a3 += bf2f(p[3]);
  }
  u16* orow = attn + ((long)b * SLQ + q) * EE + h * HD + d;
  orow[0] = f2bf(a0); orow[1] = f2bf(a1); orow[2] = f2bf(a2); orow[3] = f2bf(a3);
}

// f32 -> bf16 conversion, 8 elems/thread
__global__ __launch_bounds__(256)
void cvt_kernel(const float* __restrict__ in, u16* __restrict__ out) {
  long base = ((long)blockIdx.x * 256 + threadIdx.x) * 8;
  float4 a = *(const float4*)&in[base];
  float4 b = *(const float4*)&in[base + 4];
  s16x8 o;
  o[0] = (short)f2bf(a.x); o[1] = (short)f2bf(a.y);
  o[2] = (short)f2bf(a.z); o[3] = (short)f2bf(a.w);
  o[4] = (short)f2bf(b.x); o[5] = (short)f2bf(b.y);
  o[6] = (short)f2bf(b.z); o[7] = (short)f2bf(b.w);
  *(s16x8*)&out[base] = o;
}

__global__ __launch_bounds__(256)
void wcvt_kernel(const float* s0, const float* s1, const float* s2,
                 const float* s3, const float* s4, const float* s5,
                 const float* s6, const float* s7, const float* s8,
                 u16* __restrict__ dst) {
  int mat = blockIdx.x >> 7, part = blockIdx.x & 127;
  const float* srcs[9] = {s0, s1, s2, s3, s4, s5, s6, s7, s8};
  const float* src = srcs[mat];
  long off = (long)part * 2048 + threadIdx.x * 8;
  float4 a = *(const float4*)&src[off];
  float4 b = *(const float4*)&src[off + 4];
  s16x8 o;
  o[0] = (short)f2bf(a.x); o[1] = (short)f2bf(a.y);
  o[2] = (short)f2bf(a.z); o[3] = (short)f2bf(a.w);
  o[4] = (short)f2bf(b.x); o[5] = (short)f2bf(b.y);
  o[6] = (short)f2bf(b.z); o[7] = (short)f2bf(b.w);
  *(s16x8*)&dst[(long)mat * EE * EE + off] = o;
}

__global__ __launch_bounds__(256)
void mask_q_kernel(const float* __restrict__ in, u16* __restrict__ out,
                   const int* __restrict__ qlen) {
  long base = ((long)blockIdx.x * 256 + threadIdx.x) * 8;
  int row = (int)(base >> 9);
  int b = row >> 10, q = row & 1023;
  s16x8 o = (s16x8){0, 0, 0, 0, 0, 0, 0, 0};
  if (q < qlen[b]) {
    float4 a = *(const float4*)&in[base];
    float4 c = *(const float4*)&in[base + 4];
    o[0] = (short)f2bf(a.x); o[1] = (short)f2bf(a.y);
    o[2] = (short)f2bf(a.z); o[3] = (short)f2bf(a.w);
    o[4] = (short)f2bf(c.x); o[5] = (short)f2bf(c.y);
    o[6] = (short)f2bf(c.z); o[7] = (short)f2bf(c.w);
  }
  *(s16x8*)&out[base] = o;
}

__device__ __forceinline__ float blockSum(float v, float* red4) {
#pragma unroll
  for (int o = 32; o; o >>= 1) v += __shfl_xor(v, o);
  if ((threadIdx.x & 63) == 0) red4[threadIdx.x >> 6] = v;
  __syncthreads();
  v = red4[0] + red4[1] + red4[2] + red4[3];
  __syncthreads();
  return v;
}
__device__ __forceinline__ float blockMax(float v, float* red4) {
#pragma unroll
  for (int o = 32; o; o >>= 1) v = fmaxf(v, __shfl_xor(v, o));
  if ((threadIdx.x & 63) == 0) red4[threadIdx.x >> 6] = v;
  __syncthreads();
  v = fmaxf(fmaxf(red4[0], red4[1]), fmaxf(red4[2], red4[3]));
  __syncthreads();
  return v;
}

// fused cross softmax (8 heads) + head-mean output; invalid q rows: only zero out_w
__global__ __launch_bounds__(256)
void softmax_wmean_cross(u16* __restrict__ S, float* __restrict__ outw,
                         const int* __restrict__ qlen) {
  int row = blockIdx.x;
  int b = row >> 10, q = row & 1023;
  int t = threadIdx.x;
  float* wr = outw + (long)row * SLK + t * 8;
  if (q >= qlen[b]) {
    float4 z = {0.f, 0.f, 0.f, 0.f};
    *(float4*)wr = z; *(float4*)(wr + 4) = z;
    return;
  }
  __shared__ float red4[4];
  float acc[8] = {0, 0, 0, 0, 0, 0, 0, 0};
  for (int h = 0; h < HH; ++h) {
    u16* p = S + ((long)((b * HH + h) * SLQ + q)) * SLK + t * 8;
    s16x8 v = *(const s16x8*)p;
    float x[8]; float m = -1e30f;
#pragma unroll
    for (int j = 0; j < 8; ++j) { x[j] = bf2f((u16)v[j]); m = fmaxf(m, x[j]); }
    m = blockMax(m, red4);
    float ssum = 0.f;
#pragma unroll
    for (int j = 0; j < 8; ++j) { x[j] = __expf(x[j] - m); ssum += x[j]; }
    ssum = blockSum(ssum, red4);
    float r = 1.0f / ssum;
#pragma unroll
    for (int j = 0; j < 8; ++j) {
      float pj = x[j] * r;
      v[j] = (short)f2bf(pj);
      acc[j] += pj;
    }
    *(s16x8*)p = v;
  }
#pragma unroll
  for (int j = 0; j < 8; ++j) wr[j] = acc[j] * 0.125f;
}

template<int OUTF32>
__global__ __launch_bounds__(256)
void silu_ln_kernel(const u16* __restrict__ x1, const u16* __restrict__ x2,
                    const float* __restrict__ g, const float* __restrict__ beta,
                    const int* __restrict__ qlen, void* __restrict__ outv, int mode) {
  int row = blockIdx.x;
  int b = row >> 10, q = row & 1023;
  int t = threadIdx.x;
  if (mode && q >= qlen[b]) {
    if (mode == 1) {
      if (OUTF32) {
        float* o = (float*)outv + (long)row * EE;
        o[2 * t] = 0.f; o[2 * t + 1] = 0.f;
      } else {
        u16* o = (u16*)outv + (long)row * EE;
        *(unsigned int*)&o[2 * t] = 0u;
      }
    }
    return;
  }
  __shared__ float red4[4];
  const u16* p1 = x1 + (long)row * EE;
  const u16* p2 = x2 + (long)row * EE;
  float a0 = bf2f(p1[2 * t]) + bf2f(p2[2 * t]);
  float a1 = bf2f(p1[2 * t + 1]) + bf2f(p2[2 * t + 1]);
  a0 = a0 / (1.f + __expf(-a0));
  a1 = a1 / (1.f + __expf(-a1));
  float mu = blockSum(a0 + a1, red4) * (1.f / 512.f);
  float d0 = a0 - mu, d1 = a1 - mu;
  float var = blockSum(d0 * d0 + d1 * d1, red4) * (1.f / 512.f);
  float rs = rsqrtf(var + 1e-5f);
  float r0 = d0 * rs * g[2 * t] + beta[2 * t];
  float r1 = d1 * rs * g[2 * t + 1] + beta[2 * t + 1];
  if (OUTF32) {
    float* o = (float*)outv + (long)row * EE;
    o[2 * t] = r0; o[2 * t + 1] = r1;
  } else {
    u16* o = (u16*)outv + (long)row * EE;
    o[2 * t] = f2bf(r0); o[2 * t + 1] = f2bf(r1);
  }
}

extern "C" void kernel_launch(void* const* d_in, const int* in_sizes, int n_in,
                              void* d_out, int out_size, void* d_ws, size_t ws_size,
                              hipStream_t stream) {
  const float* queries = (const float*)d_in[0];
  const float* keys    = (const float*)d_in[1];
  const int*   qlen    = (const int*)d_in[2];
  const float* cWq = (const float*)d_in[3],  *cbq = (const float*)d_in[4];
  const float* cWk = (const float*)d_in[5],  *cbk = (const float*)d_in[6];
  const float* cWv = (const float*)d_in[7],  *cbv = (const float*)d_in[8];
  const float* cWo = (const float*)d_in[9],  *cbo = (const float*)d_in[10];
  const float* sWq = (const float*)d_in[11], *sbq = (const float*)d_in[12];
  const float* sWk = (const float*)d_in[13], *sbk = (const float*)d_in[14];
  const float* sWv = (const float*)d_in[15], *sbv = (const float*)d_in[16];
  const float* sWo = (const float*)d_in[17], *sbo = (const float*)d_in[18];
  const float* Wf  = (const float*)d_in[19], *bfb = (const float*)d_in[20];
  const float* g_cross = (const float*)d_in[21], *b_cross = (const float*)d_in[22];
  const float* g_ffn   = (const float*)d_in[23], *b_ffn   = (const float*)d_in[24];
  const float* g_self  = (const float*)d_in[25], *b_self  = (const float*)d_in[26];

  float* out_q = (float*)d_out;
  float* out_w = out_q + (long)BB * SLQ * EE;

  u16* ws = (u16*)d_ws;
  u16* S     = ws;                               // 67,108,864 u16
  u16* Qc    = S   + (long)BB * HH * SLQ * SLK;
  u16* Kc    = Qc  + (long)BB * HH * SLQ * HD;
  u16* Vt    = Kc  + (long)BB * HH * SLK * HD;
  u16* q0    = Vt  + (long)BB * HH * SLK * HD;
  u16* keysb = q0  + (long)BB * SLQ * EE;
  u16* attn  = keysb + (long)BB * SLK * EE;
  u16* proj  = attn + (long)BB * SLQ * EE;
  u16* q1    = proj + (long)BB * SLQ * EE;
  u16* fbuf  = q1  + (long)BB * SLQ * EE;
  u16* q2    = fbuf + (long)BB * SLQ * EE;
  u16* Wb    = q2  + (long)BB * SLQ * EE;
  const long WSLOT = (long)EE * EE;
  u16* Cp    = Wb + 9 * WSLOT;                   // 32768*4*64 bf16 PV partials

  // self-flash partials overlay the S region (S is dead by then)
  float* OpS = (float*)S;                        // 32768*8*64 f32 = 64 MiB
  float* mlS = (float*)(S + 33554432);           // 32768*8 float2

  u16* bWq = Wb + 0 * WSLOT; u16* bWk = Wb + 1 * WSLOT; u16* bWv = Wb + 2 * WSLOT;
  u16* bWo = Wb + 3 * WSLOT; u16* bsWq = Wb + 4 * WSLOT; u16* bsWk = Wb + 5 * WSLOT;
  u16* bsWv = Wb + 6 * WSLOT; u16* bsWo = Wb + 7 * WSLOT; u16* bWf = Wb + 8 * WSLOT;

  dim3 blk(256);
  const int MQ = BB * SLQ;   // 4096
  const int MK = BB * SLK;   // 8192

  mask_q_kernel<<<dim3((MQ * EE) / 2048), blk, 0, stream>>>(queries, q0, qlen);
  cvt_kernel<<<dim3((MK * EE) / 2048), blk, 0, stream>>>(keys, keysb);
  wcvt_kernel<<<dim3(9 * 128), blk, 0, stream>>>(cWq, cWk, cWv, cWo, sWq, sWk, sWv, sWo, Wf, Wb);

  // cross projections
  gemm_nt<64, 128, 1, 2><<<dim3(EE / 128, MQ / 64, 1), blk, 0, stream>>>(
      q0, bWq, cbq, Qc, MQ, EE, EE, EE, EE, 0, 0, 0, 0, 1.0f, SLQ, qlen);
  gemm_nt<128, 128, 1, 0><<<dim3(EE / 128, MK / 128, 1), blk, 0, stream>>>(
      keysb, bWk, cbk, Kc, MK, EE, EE, EE, EE, 0, 0, 0, 0, 1.0f, SLK, qlen);
  gemm_nt<128, 128, 2, 0><<<dim3(EE / 128, MK / 128, 1), blk, 0, stream>>>(
      keysb, bWv, cbv, Vt, MK, EE, EE, EE, EE, 0, 0, 0, 0, 1.0f, SLK, qlen);

  // S = Q K^T * 1/8  (skip invalid q tiles)
  gemm_nt<128, 128, 0, 1><<<dim3(SLK / 128, SLQ / 128, BB * HH), blk, 0, stream>>>(
      Qc, Kc, nullptr, S, SLQ, SLK, HD, HD, HD, SLK,
      (long)SLQ * HD, (long)SLK * HD, (long)SLQ * SLK, 0.125f, 0, qlen);

  softmax_wmean_cross<<<dim3(BB * SLQ), blk, 0, stream>>>(S, out_w, qlen);

  // cross PV: split-K (4 x 512) bf16 partials + combine
  gemm_nt<128, 64, 4, 1><<<dim3(4, SLQ / 128, BB * HH), blk, 0, stream>>>(
      S, Vt, nullptr, Cp, SLQ, HD, 512, SLK, SLK, 0,
      (long)SLQ * SLK, (long)HD * SLK, 0, 1.0f, 512, qlen);
  pv_combine<<<dim3(2048), blk, 0, stream>>>(Cp, attn, qlen);

  gemm_nt<64, 128, 0, 2><<<dim3(EE / 128, MQ / 64, 1), blk, 0, stream>>>(
      attn, bWo, cbo, proj, MQ, EE, EE, EE, EE, EE, 0, 0, 0, 1.0f, SLQ, qlen);

  silu_ln_kernel<0><<<dim3(MQ), blk, 0, stream>>>(proj, q0, g_cross, b_cross, qlen, q1, 2);

  gemm_nt<64, 128, 0, 2><<<dim3(EE / 128, MQ / 64, 1), blk, 0, stream>>>(
      q1, bWf, bfb, fbuf, MQ, EE, EE, EE, EE, EE, 0, 0, 0, 1.0f, SLQ, qlen);

  silu_ln_kernel<0><<<dim3(MQ), blk, 0, stream>>>(q1, fbuf, g_ffn, b_ffn, qlen, q2, 1);

  // self projections
  gemm_nt<64, 128, 1, 2><<<dim3(EE / 128, MQ / 64, 1), blk, 0, stream>>>(
      q2, bsWq, sbq, Qc, MQ, EE, EE, EE, EE, 0, 0, 0, 0, 1.0f, SLQ, qlen);
  gemm_nt<64, 128, 1, 2><<<dim3(EE / 128, MQ / 64, 1), blk, 0, stream>>>(
      q2, bsWk, sbk, Kc, MQ, EE, EE, EE, EE, 0, 0, 0, 0, 1.0f, SLQ, qlen);
  gemm_nt<64, 128, 2, 2><<<dim3(EE / 128, MQ / 64, 1), blk, 0, stream>>>(
      q2, bsWv, sbv, Vt, MQ, EE, EE, EE, EE, 0, 0, 0, 0, 1.0f, SLQ, qlen);

  // self attention: chunked flash + combine (partials overlay S)
  self_flash_chunk<<<dim3(16, 32, 8), blk, 0, stream>>>(Qc, Kc, Vt, OpS, mlS, qlen);
  self_combine<<<dim3(2048), blk, 0, stream>>>(OpS, mlS, attn, qlen);

  gemm_nt<64, 128, 0, 2><<<dim3(EE / 128, MQ / 64, 1), blk, 0, stream>>>(
      attn, bsWo, sbo, proj, MQ, EE, EE, EE, EE, EE, 0, 0, 0, 1.0f, SLQ, qlen);

  silu_ln_kernel<1><<<dim3(MQ), blk, 0, stream>>>(q2, proj, g_self, b_self, qlen, out_q, 1);
}

// Round 5
// 373.064 us; speedup vs baseline: 1.3077x; 1.0334x over previous
//
#include <hip/hip_runtime.h>

#define BB 4
#define SLQ 1024
#define SLK 2048
#define EE 512
#define HH 8
#define HD 64

typedef unsigned short u16;
typedef __attribute__((ext_vector_type(8))) short s16x8;
typedef __attribute__((ext_vector_type(4))) float f32x4;

__device__ __forceinline__ float bf2f(u16 u) {
  union { unsigned int i; float f; } v; v.i = ((unsigned int)u) << 16; return v.f;
}
__device__ __forceinline__ u16 f2bf(float f) {
  union { float f; unsigned int i; } v; v.f = f;
  unsigned int i = v.i;
  return (u16)((i + 0x7fffu + ((i >> 16) & 1u)) >> 16);
}

__device__ __forceinline__ void async16(const u16* g, u16* l) {
  __builtin_amdgcn_global_load_lds(
      (const __attribute__((address_space(1))) unsigned int*)g,
      (__attribute__((address_space(3))) unsigned int*)l, 16, 0, 0);
}

// NT GEMM: C[m,n] = alpha * sum_k A[m,k]*B[n,k] + bias[n]   (A,B bf16; bias f32)
// MODE 0: C + z*sCz row-major, LDS-staged coalesced C write
// MODE 1: head-split [B,H,Lsub,64]; MODE 2: head-split transposed [B,H,64,Lsub]
// SKIPQ 0: none; 1: b=z>>3, skip tileM>=qlen[b]; 2: b=tileM>>10 (Lsub=1024)
template<int BM, int BN, int MODE, int SKIPQ>
__global__ __launch_bounds__(256, 2)
void gemm_nt(const u16* __restrict__ A, const u16* __restrict__ Bm,
             const float* __restrict__ bias, u16* __restrict__ C,
             int M, int N, int K, int lda, int ldb, int ldc,
             long sAz, long sBz, long sCz, float alpha, int Lsub,
             const int* __restrict__ qlen)
{
  constexpr int WTM = BM / 2, WTN = BN / 2;
  constexpr int MI = WTM / 16, NI = WTN / 16;

  const int z = blockIdx.z;
  const int tileM = blockIdx.y * BM;
  const int tileN = blockIdx.x * BN;

  if (SKIPQ == 1) { if (tileM >= qlen[z >> 3]) return; }
  if (SKIPQ == 2) { int b = tileM >> 10; if ((tileM & 1023) >= qlen[b]) return; }

  __shared__ __align__(16) u16 smem[(BM + BN) * 32];
  u16* ldsA = smem;
  u16* ldsB = smem + BM * 32;

  const int t = threadIdx.x;
  const int lane = t & 63;
  const int wave = t >> 6;
  const int waveM = wave >> 1;
  const int waveN = wave & 1;
  const int lm = lane & 15;
  const int kg = lane >> 4;

  const u16* Ab = A + (long)z * sAz + (long)tileM * lda;
  const u16* Bb = Bm + (long)z * sBz + (long)tileN * ldb;

  f32x4 acc[MI][NI];
#pragma unroll
  for (int i = 0; i < MI; ++i)
#pragma unroll
    for (int j = 0; j < NI; ++j) acc[i][j] = (f32x4){0.f, 0.f, 0.f, 0.f};

  for (int kt = 0; kt < K; kt += 32) {
    __syncthreads();
#pragma unroll
    for (int i = 0; i < (BM * 4) / 256; ++i) {
      int c = i * 256 + t;
      async16(Ab + (long)(c >> 2) * lda + kt + (c & 3) * 8, ldsA + (c - lane) * 8);
    }
#pragma unroll
    for (int i = 0; i < (BN * 4) / 256; ++i) {
      int c = i * 256 + t;
      async16(Bb + (long)(c >> 2) * ldb + kt + (c & 3) * 8, ldsB + (c - lane) * 8);
    }
    __syncthreads();

    s16x8 aF[MI], bF[NI];
#pragma unroll
    for (int i = 0; i < MI; ++i)
      aF[i] = *(const s16x8*)&ldsA[(waveM * WTM + i * 16 + lm) * 32 + kg * 8];
#pragma unroll
    for (int j = 0; j < NI; ++j)
      bF[j] = *(const s16x8*)&ldsB[(waveN * WTN + j * 16 + lm) * 32 + kg * 8];
#pragma unroll
    for (int i = 0; i < MI; ++i)
#pragma unroll
      for (int j = 0; j < NI; ++j)
        acc[i][j] = __builtin_amdgcn_mfma_f32_16x16x32_bf16(aF[i], bF[j], acc[i][j], 0, 0, 0);
  }

  if (MODE == 0) {
    // LDS-staged coalesced C write: 32-row chunks, full-row dwordx4 stores
#pragma unroll
    for (int c = 0; c < BM / 32; ++c) {
      const int rlo = c * 32;
      __syncthreads();
#pragma unroll
      for (int i = 0; i < MI; ++i) {
        int mbase = waveM * WTM + i * 16;
        if (mbase >= rlo && mbase < rlo + 32) {
#pragma unroll
          for (int j = 0; j < NI; ++j) {
            int n = waveN * WTN + j * 16 + lm;
            float bv = bias ? bias[tileN + n] : 0.0f;
#pragma unroll
            for (int r = 0; r < 4; ++r) {
              int m = mbase + kg * 4 + r;
              smem[(m - rlo) * BN + n] = f2bf(acc[i][j][r] * alpha + bv);
            }
          }
        }
      }
      __syncthreads();
#pragma unroll
      for (int v = 0; v < (32 * BN) / (256 * 8); ++v) {
        int idx = v * 256 + t;
        int row = idx / (BN / 8), col8 = idx % (BN / 8);
        *(uint4*)&C[(long)z * sCz + (long)(tileM + rlo + row) * ldc + tileN + col8 * 8] =
            *(const uint4*)&smem[row * BN + col8 * 8];
      }
    }
  } else {
#pragma unroll
    for (int j = 0; j < NI; ++j) {
      int n = tileN + waveN * WTN + j * 16 + lm;
      float bv = bias ? bias[n] : 0.0f;
#pragma unroll
      for (int i = 0; i < MI; ++i) {
#pragma unroll
        for (int r = 0; r < 4; ++r) {
          int m = tileM + waveM * WTM + i * 16 + kg * 4 + r;
          float v = acc[i][j][r] * alpha + bv;
          if (MODE == 1) {
            int b = m / Lsub, l = m - b * Lsub;
            int h = n >> 6, d = n & 63;
            C[(((long)(b * HH + h) * Lsub + l) << 6) + d] = f2bf(v);
          } else {
            int b = m / Lsub, l = m - b * Lsub;
            int h = n >> 6, d = n & 63;
            C[((long)(b * HH + h) * HD + d) * Lsub + l] = f2bf(v);
          }
        }
      }
    }
  }
}

// cross softmax stats + head-mean weights. Read-only over S.
// wave w handles heads 2w, 2w+1; writes (m,l) stats + f32 out_w.
__global__ __launch_bounds__(256)
void softmax_stats_wmean(const u16* __restrict__ S, float* __restrict__ outw,
                         float2* __restrict__ stats, const int* __restrict__ qlen) {
  int row = blockIdx.x;               // b*1024 + q
  int b = row >> 10, q = row & 1023;
  int t = threadIdx.x, lane = t & 63, w = t >> 6;
  float* wr = outw + (long)row * SLK;
  if (q >= qlen[b]) {
    float4 z = {0.f, 0.f, 0.f, 0.f};
    *(float4*)(wr + t * 8) = z; *(float4*)(wr + t * 8 + 4) = z;
    return;
  }
  __shared__ float acc4[4][2048];
#pragma unroll
  for (int hh = 0; hh < 2; ++hh) {
    int h = 2 * w + hh;
    const u16* p = S + ((long)((b * HH + h) * SLQ + q)) * SLK;
    float x[4][8];
    float m = -1e30f;
#pragma unroll
    for (int c = 0; c < 4; ++c) {
      s16x8 v = *(const s16x8*)(p + c * 512 + lane * 8);
#pragma unroll
      for (int j = 0; j < 8; ++j) { x[c][j] = bf2f((u16)v[j]); m = fmaxf(m, x[c][j]); }
    }
#pragma unroll
    for (int o = 1; o <= 32; o <<= 1) m = fmaxf(m, __shfl_xor(m, o));
    float s = 0.f;
#pragma unroll
    for (int c = 0; c < 4; ++c)
#pragma unroll
      for (int j = 0; j < 8; ++j) { x[c][j] = __expf(x[c][j] - m); s += x[c][j]; }
#pragma unroll
    for (int o = 1; o <= 32; o <<= 1) s += __shfl_xor(s, o);
    if (lane == 0) stats[(long)(b * HH + h) * SLQ + q] = (float2){m, s};
    float sc = 0.125f / s;
#pragma unroll
    for (int c = 0; c < 4; ++c) {
      float4 v0 = {x[c][0] * sc, x[c][1] * sc, x[c][2] * sc, x[c][3] * sc};
      float4 v1 = {x[c][4] * sc, x[c][5] * sc, x[c][6] * sc, x[c][7] * sc};
      if (hh == 0) {
        *(float4*)&acc4[w][c * 512 + lane * 8] = v0;
        *(float4*)&acc4[w][c * 512 + lane * 8 + 4] = v1;
      } else {
        float4 a0 = *(const float4*)&acc4[w][c * 512 + lane * 8];
        float4 a1 = *(const float4*)&acc4[w][c * 512 + lane * 8 + 4];
        a0.x += v0.x; a0.y += v0.y; a0.z += v0.z; a0.w += v0.w;
        a1.x += v1.x; a1.y += v1.y; a1.z += v1.z; a1.w += v1.w;
        *(float4*)&acc4[w][c * 512 + lane * 8] = a0;
        *(float4*)&acc4[w][c * 512 + lane * 8 + 4] = a1;
      }
    }
  }
  __syncthreads();
#pragma unroll
  for (int u = 0; u < 2; ++u) {
    int k = t * 8 + u * 4;
    float4 s0 = *(const float4*)&acc4[0][k];
    float4 s1 = *(const float4*)&acc4[1][k];
    float4 s2 = *(const float4*)&acc4[2][k];
    float4 s3 = *(const float4*)&acc4[3][k];
    float4 o = {s0.x + s1.x + s2.x + s3.x, s0.y + s1.y + s2.y + s3.y,
                s0.z + s1.z + s2.z + s3.z, s0.w + s1.w + s2.w + s3.w};
    *(float4*)(wr + k) = o;
  }
}

// cross PV with on-the-fly exp(s-m): split-K 512, f32 partials
__global__ __launch_bounds__(256, 2)
void pv_cross(const u16* __restrict__ S, const u16* __restrict__ Vt,
              const float2* __restrict__ stats, float* __restrict__ Opart,
              const int* __restrict__ qlen)
{
  const int qt = blockIdx.x;           // 16 q-tiles of 64
  const int bh = blockIdx.y;           // 32
  const int kc = blockIdx.z;           // 4 chunks of 512 keys
  const int b = bh >> 3;
  if (qt * 64 >= qlen[b]) return;

  __shared__ __align__(16) u16 Sl[64 * 72];
  __shared__ __align__(16) u16 Vl[64 * 72];

  const int t = threadIdx.x, lane = t & 63, w = t >> 6;
  const int lm = lane & 15, quad = lane >> 4;

  const u16* Sb = S + ((long)bh * SLQ + qt * 64) * SLK;
  const u16* Vb = Vt + (long)bh * HD * SLK;
  const float mrow = stats[(long)bh * SLQ + qt * 64 + w * 16 + lm].x;

  f32x4 O[4];
#pragma unroll
  for (int n = 0; n < 4; ++n) O[n] = (f32x4){0.f, 0.f, 0.f, 0.f};

  const int srow = t >> 3, sk8 = t & 7;

  for (int ks = 0; ks < 8; ++ks) {
    const int k0 = kc * 512 + ks * 64;
    __syncthreads();
    // stage S chunk [64 q][64 k] (pad 72) and V chunk [64 d][64 k] (pad 72)
    *(uint4*)&Sl[srow * 72 + sk8 * 8] = *(const uint4*)(Sb + (long)srow * SLK + k0 + sk8 * 8);
    *(uint4*)&Sl[(srow + 32) * 72 + sk8 * 8] =
        *(const uint4*)(Sb + (long)(srow + 32) * SLK + k0 + sk8 * 8);
    *(uint4*)&Vl[srow * 72 + sk8 * 8] = *(const uint4*)(Vb + (long)srow * SLK + k0 + sk8 * 8);
    *(uint4*)&Vl[(srow + 32) * 72 + sk8 * 8] =
        *(const uint4*)(Vb + (long)(srow + 32) * SLK + k0 + sk8 * 8);
    __syncthreads();

#pragma unroll
    for (int kk = 0; kk < 2; ++kk) {
      s16x8 raw = *(const s16x8*)&Sl[(w * 16 + lm) * 72 + kk * 32 + quad * 8];
      s16x8 aP;
#pragma unroll
      for (int j = 0; j < 8; ++j)
        aP[j] = (short)f2bf(__expf(bf2f((u16)raw[j]) - mrow));
#pragma unroll
      for (int n = 0; n < 4; ++n) {
        s16x8 bV = *(const s16x8*)&Vl[(n * 16 + lm) * 72 + kk * 32 + quad * 8];
        O[n] = __builtin_amdgcn_mfma_f32_16x16x32_bf16(aP, bV, O[n], 0, 0, 0);
      }
    }
  }

#pragma unroll
  for (int r = 0; r < 4; ++r) {
    int qrow = qt * 64 + w * 16 + quad * 4 + r;
#pragma unroll
    for (int n = 0; n < 4; ++n)
      Opart[(((long)bh * SLQ + qrow) * 4 + kc) * 64 + n * 16 + lm] = O[n][r];
  }
}

// sum 4 split-K f32 partials, apply 1/l -> attn bf16
__global__ __launch_bounds__(256)
void pv_combine_cross(const float* __restrict__ Opart, const float2* __restrict__ stats,
                      u16* __restrict__ attn, const int* __restrict__ qlen)
{
  int gr = blockIdx.x * 16 + (threadIdx.x >> 4);
  int bh = gr >> 10, q = gr & 1023;
  int b = bh >> 3, h = bh & 7;
  if (q >= qlen[b]) return;
  int d = (threadIdx.x & 15) * 4;
  float ax = 0.f, ay = 0.f, az = 0.f, aw = 0.f;
#pragma unroll
  for (int c = 0; c < 4; ++c) {
    float4 o = *(const float4*)&Opart[((long)gr * 4 + c) * 64 + d];
    ax += o.x; ay += o.y; az += o.z; aw += o.w;
  }
  float inv = 1.0f / stats[gr].y;
  u16 o0 = f2bf(ax * inv), o1 = f2bf(ay * inv), o2 = f2bf(az * inv), o3 = f2bf(aw * inv);
  unsigned int lo = (unsigned int)o0 | ((unsigned int)o1 << 16);
  unsigned int hi = (unsigned int)o2 | ((unsigned int)o3 << 16);
  *(uint2*)&attn[((long)b * SLQ + q) * EE + h * HD + d] = (uint2){lo, hi};
}

// ------------- self-attention: chunked flash (one K-chunk per block) --------
__global__ __launch_bounds__(256, 3)
void self_flash_chunk(const u16* __restrict__ Qc, const u16* __restrict__ Kc,
                      const u16* __restrict__ Vt, float* __restrict__ Opart,
                      float* __restrict__ ml, const int* __restrict__ qlen)
{
  const int qt = blockIdx.x;
  const int bh = blockIdx.y;
  const int ck = blockIdx.z;
  const int b = bh >> 3;
  const int kmax = qlen[b];
  const int k0 = ck * 128;
  if (qt * 64 >= kmax || k0 >= kmax) return;

  __shared__ __align__(16) u16 Kt[128 * 72];
  __shared__ __align__(16) u16 Vl[64 * 136];
  __shared__ __align__(16) u16 Pl[4 * 16 * 136];

  const int t = threadIdx.x, lane = t & 63, w = t >> 6;
  const int col = lane & 15, quad = lane >> 4;

  const u16* Qb = Qc + (long)bh * SLQ * HD;
  const u16* Kb = Kc + (long)bh * SLQ * HD;
  const u16* Vb = Vt + (long)bh * HD * SLQ;

  for (int c = t; c < 1024; c += 256) {
    int r = c >> 3, c8 = c & 7;
    *(uint4*)&Kt[r * 72 + c8 * 8] = *(const uint4*)(Kb + (long)(k0 + r) * HD + c8 * 8);
  }
  for (int c = t; c < 1024; c += 256) {
    int d = c >> 4, c16 = c & 15;
    *(uint4*)&Vl[d * 136 + c16 * 8] = *(const uint4*)(Vb + (long)d * SLQ + k0 + c16 * 8);
  }
  s16x8 aQ[2];
#pragma unroll
  for (int kk = 0; kk < 2; ++kk)
    aQ[kk] = *(const s16x8*)(Qb + (long)(qt * 64 + w * 16 + col) * HD + kk * 32 + quad * 8);
  __syncthreads();

  f32x4 s[8];
#pragma unroll
  for (int j = 0; j < 8; ++j) s[j] = (f32x4){0.f, 0.f, 0.f, 0.f};
#pragma unroll
  for (int j = 0; j < 8; ++j)
#pragma unroll
    for (int kk = 0; kk < 2; ++kk) {
      s16x8 bK = *(const s16x8*)&Kt[(j * 16 + col) * 72 + kk * 32 + quad * 8];
      s[j] = __builtin_amdgcn_mfma_f32_16x16x32_bf16(aQ[kk], bK, s[j], 0, 0, 0);
    }
#pragma unroll
  for (int j = 0; j < 8; ++j) {
    bool ok = (k0 + j * 16 + col) < kmax;
#pragma unroll
    for (int r = 0; r < 4; ++r)
      s[j][r] = ok ? s[j][r] * 0.125f : -1e30f;
  }
  float mr[4], lr[4];
#pragma unroll
  for (int r = 0; r < 4; ++r) {
    float tm = s[0][r];
#pragma unroll
    for (int j = 1; j < 8; ++j) tm = fmaxf(tm, s[j][r]);
#pragma unroll
    for (int o = 1; o <= 8; o <<= 1) tm = fmaxf(tm, __shfl_xor(tm, o));
    mr[r] = tm;
    float ps = 0.f;
#pragma unroll
    for (int j = 0; j < 8; ++j) {
      float p = __expf(s[j][r] - tm);
      s[j][r] = p;
      ps += p;
    }
#pragma unroll
    for (int o = 1; o <= 8; o <<= 1) ps += __shfl_xor(ps, o);
    lr[r] = ps;
  }
  u16* Pw = Pl + w * 16 * 136;
#pragma unroll
  for (int j = 0; j < 8; ++j)
#pragma unroll
    for (int r = 0; r < 4; ++r)
      Pw[(quad * 4 + r) * 136 + j * 16 + col] = f2bf(s[j][r]);

  f32x4 O[4];
#pragma unroll
  for (int n = 0; n < 4; ++n) O[n] = (f32x4){0.f, 0.f, 0.f, 0.f};
#pragma unroll
  for (int kk = 0; kk < 4; ++kk) {
    s16x8 aP = *(const s16x8*)&Pw[col * 136 + kk * 32 + quad * 8];
#pragma unroll
    for (int n = 0; n < 4; ++n) {
      s16x8 bV = *(const s16x8*)&Vl[(n * 16 + col) * 136 + kk * 32 + quad * 8];
      O[n] = __builtin_amdgcn_mfma_f32_16x16x32_bf16(aP, bV, O[n], 0, 0, 0);
    }
  }
#pragma unroll
  for (int r = 0; r < 4; ++r) {
    int q = qt * 64 + w * 16 + quad * 4 + r;
    long gq = (long)bh * SLQ + q;
#pragma unroll
    for (int n = 0; n < 4; ++n)
      Opart[(gq * 8 + ck) * 64 + n * 16 + col] = O[n][r];
    if (col == 0) {
      ml[(gq * 8 + ck) * 2] = mr[r];
      ml[(gq * 8 + ck) * 2 + 1] = lr[r];
    }
  }
}

__global__ __launch_bounds__(256)
void self_combine(const float* __restrict__ Opart, const float* __restrict__ ml,
                  u16* __restrict__ attn, const int* __restrict__ qlen)
{
  int gr = blockIdx.x * 16 + (threadIdx.x >> 4);
  int bh = gr >> 10, q = gr & 1023;
  int b = bh >> 3, h = bh & 7;
  int kmax = qlen[b];
  if (q >= kmax) return;
  int NC = (kmax + 127) >> 7;
  int d = (threadIdx.x & 15) * 4;
  long base = (long)gr * 8;
  float M = -1e30f;
  for (int c = 0; c < NC; ++c) M = fmaxf(M, ml[(base + c) * 2]);
  float L = 0.f;
  float ax = 0.f, ay = 0.f, az = 0.f, aw = 0.f;
  for (int c = 0; c < NC; ++c) {
    float wgt = __expf(ml[(base + c) * 2] - M);
    L += ml[(base + c) * 2 + 1] * wgt;
    float4 o = *(const float4*)&Opart[(base + c) * 64 + d];
    ax += o.x * wgt; ay += o.y * wgt; az += o.z * wgt; aw += o.w * wgt;
  }
  float inv = 1.0f / L;
  u16 o0 = f2bf(ax * inv), o1 = f2bf(ay * inv), o2 = f2bf(az * inv), o3 = f2bf(aw * inv);
  unsigned int lo = (unsigned int)o0 | ((unsigned int)o1 << 16);
  unsigned int hi = (unsigned int)o2 | ((unsigned int)o3 << 16);
  *(uint2*)&attn[((long)b * SLQ + q) * EE + h * HD + d] = (uint2){lo, hi};
}

__global__ __launch_bounds__(256)
void cvt_kernel(const float* __restrict__ in, u16* __restrict__ out) {
  long base = ((long)blockIdx.x * 256 + threadIdx.x) * 8;
  float4 a = *(const float4*)&in[base];
  float4 b = *(const float4*)&in[base + 4];
  s16x8 o;
  o[0] = (short)f2bf(a.x); o[1] = (short)f2bf(a.y);
  o[2] = (short)f2bf(a.z); o[3] = (short)f2bf(a.w);
  o[4] = (short)f2bf(b.x); o[5] = (short)f2bf(b.y);
  o[6] = (short)f2bf(b.z); o[7] = (short)f2bf(b.w);
  *(s16x8*)&out[base] = o;
}

__global__ __launch_bounds__(256)
void wcvt_kernel(const float* s0, const float* s1, const float* s2,
                 const float* s3, const float* s4, const float* s5,
                 const float* s6, const float* s7, const float* s8,
                 u16* __restrict__ dst) {
  int mat = blockIdx.x >> 7, part = blockIdx.x & 127;
  const float* srcs[9] = {s0, s1, s2, s3, s4, s5, s6, s7, s8};
  const float* src = srcs[mat];
  long off = (long)part * 2048 + threadIdx.x * 8;
  float4 a = *(const float4*)&src[off];
  float4 b = *(const float4*)&src[off + 4];
  s16x8 o;
  o[0] = (short)f2bf(a.x); o[1] = (short)f2bf(a.y);
  o[2] = (short)f2bf(a.z); o[3] = (short)f2bf(a.w);
  o[4] = (short)f2bf(b.x); o[5] = (short)f2bf(b.y);
  o[6] = (short)f2bf(b.z); o[7] = (short)f2bf(b.w);
  *(s16x8*)&dst[(long)mat * EE * EE + off] = o;
}

__global__ __launch_bounds__(256)
void mask_q_kernel(const float* __restrict__ in, u16* __restrict__ out,
                   const int* __restrict__ qlen) {
  long base = ((long)blockIdx.x * 256 + threadIdx.x) * 8;
  int row = (int)(base >> 9);
  int b = row >> 10, q = row & 1023;
  s16x8 o = (s16x8){0, 0, 0, 0, 0, 0, 0, 0};
  if (q < qlen[b]) {
    float4 a = *(const float4*)&in[base];
    float4 c = *(const float4*)&in[base + 4];
    o[0] = (short)f2bf(a.x); o[1] = (short)f2bf(a.y);
    o[2] = (short)f2bf(a.z); o[3] = (short)f2bf(a.w);
    o[4] = (short)f2bf(c.x); o[5] = (short)f2bf(c.y);
    o[6] = (short)f2bf(c.z); o[7] = (short)f2bf(c.w);
  }
  *(s16x8*)&out[base] = o;
}

__device__ __forceinline__ float blockSum(float v, float* red4) {
#pragma unroll
  for (int o = 32; o; o >>= 1) v += __shfl_xor(v, o);
  if ((threadIdx.x & 63) == 0) red4[threadIdx.x >> 6] = v;
  __syncthreads();
  v = red4[0] + red4[1] + red4[2] + red4[3];
  __syncthreads();
  return v;
}

template<int OUTF32>
__global__ __launch_bounds__(256)
void silu_ln_kernel(const u16* __restrict__ x1, const u16* __restrict__ x2,
                    const float* __restrict__ g, const float* __restrict__ beta,
                    const int* __restrict__ qlen, void* __restrict__ outv, int mode) {
  int row = blockIdx.x;
  int b = row >> 10, q = row & 1023;
  int t = threadIdx.x;
  if (mode && q >= qlen[b]) {
    if (mode == 1) {
      if (OUTF32) {
        float* o = (float*)outv + (long)row * EE;
        o[2 * t] = 0.f; o[2 * t + 1] = 0.f;
      } else {
        u16* o = (u16*)outv + (long)row * EE;
        *(unsigned int*)&o[2 * t] = 0u;
      }
    }
    return;
  }
  __shared__ float red4[4];
  const u16* p1 = x1 + (long)row * EE;
  const u16* p2 = x2 + (long)row * EE;
  float a0 = bf2f(p1[2 * t]) + bf2f(p2[2 * t]);
  float a1 = bf2f(p1[2 * t + 1]) + bf2f(p2[2 * t + 1]);
  a0 = a0 / (1.f + __expf(-a0));
  a1 = a1 / (1.f + __expf(-a1));
  float mu = blockSum(a0 + a1, red4) * (1.f / 512.f);
  float d0 = a0 - mu, d1 = a1 - mu;
  float var = blockSum(d0 * d0 + d1 * d1, red4) * (1.f / 512.f);
  float rs = rsqrtf(var + 1e-5f);
  float r0 = d0 * rs * g[2 * t] + beta[2 * t];
  float r1 = d1 * rs * g[2 * t + 1] + beta[2 * t + 1];
  if (OUTF32) {
    float* o = (float*)outv + (long)row * EE;
    o[2 * t] = r0; o[2 * t + 1] = r1;
  } else {
    u16* o = (u16*)outv + (long)row * EE;
    o[2 * t] = f2bf(r0); o[2 * t + 1] = f2bf(r1);
  }
}

extern "C" void kernel_launch(void* const* d_in, const int* in_sizes, int n_in,
                              void* d_out, int out_size, void* d_ws, size_t ws_size,
                              hipStream_t stream) {
  const float* queries = (const float*)d_in[0];
  const float* keys    = (const float*)d_in[1];
  const int*   qlen    = (const int*)d_in[2];
  const float* cWq = (const float*)d_in[3],  *cbq = (const float*)d_in[4];
  const float* cWk = (const float*)d_in[5],  *cbk = (const float*)d_in[6];
  const float* cWv = (const float*)d_in[7],  *cbv = (const float*)d_in[8];
  const float* cWo = (const float*)d_in[9],  *cbo = (const float*)d_in[10];
  const float* sWq = (const float*)d_in[11], *sbq = (const float*)d_in[12];
  const float* sWk = (const float*)d_in[13], *sbk = (const float*)d_in[14];
  const float* sWv = (const float*)d_in[15], *sbv = (const float*)d_in[16];
  const float* sWo = (const float*)d_in[17], *sbo = (const float*)d_in[18];
  const float* Wf  = (const float*)d_in[19], *bfb = (const float*)d_in[20];
  const float* g_cross = (const float*)d_in[21], *b_cross = (const float*)d_in[22];
  const float* g_ffn   = (const float*)d_in[23], *b_ffn   = (const float*)d_in[24];
  const float* g_self  = (const float*)d_in[25], *b_self  = (const float*)d_in[26];

  float* out_q = (float*)d_out;
  float* out_w = out_q + (long)BB * SLQ * EE;

  u16* ws = (u16*)d_ws;
  u16* S     = ws;                               // 67,108,864 u16
  u16* Qc    = S   + (long)BB * HH * SLQ * SLK;
  u16* Kc    = Qc  + (long)BB * HH * SLQ * HD;
  u16* Vt    = Kc  + (long)BB * HH * SLK * HD;
  u16* q0    = Vt  + (long)BB * HH * SLK * HD;
  u16* keysb = q0  + (long)BB * SLQ * EE;
  u16* attn  = keysb + (long)BB * SLK * EE;
  u16* proj  = attn + (long)BB * SLQ * EE;
  u16* q1    = proj + (long)BB * SLQ * EE;
  u16* fbuf  = q1  + (long)BB * SLQ * EE;
  u16* q2    = fbuf + (long)BB * SLQ * EE;
  u16* Wb    = q2  + (long)BB * SLQ * EE;
  const long WSLOT = (long)EE * EE;
  float* CpF   = (float*)(Wb + 9 * WSLOT);       // 32768*4*64 f32 PV partials (33.5 MB)
  float2* stat = (float2*)((u16*)CpF + 33554432);// 32768 float2 (256 KB)

  // self-flash partials overlay the S region (S dead by then)
  float* OpS = (float*)S;
  float* mlS = (float*)(S + 33554432);

  u16* bWq = Wb + 0 * WSLOT; u16* bWk = Wb + 1 * WSLOT; u16* bWv = Wb + 2 * WSLOT;
  u16* bWo = Wb + 3 * WSLOT; u16* bsWq = Wb + 4 * WSLOT; u16* bsWk = Wb + 5 * WSLOT;
  u16* bsWv = Wb + 6 * WSLOT; u16* bsWo = Wb + 7 * WSLOT; u16* bWf = Wb + 8 * WSLOT;

  dim3 blk(256);
  const int MQ = BB * SLQ;   // 4096
  const int MK = BB * SLK;   // 8192

  mask_q_kernel<<<dim3((MQ * EE) / 2048), blk, 0, stream>>>(queries, q0, qlen);
  cvt_kernel<<<dim3((MK * EE) / 2048), blk, 0, stream>>>(keys, keysb);
  wcvt_kernel<<<dim3(9 * 128), blk, 0, stream>>>(cWq, cWk, cWv, cWo, sWq, sWk, sWv, sWo, Wf, Wb);

  // cross projections
  gemm_nt<64, 128, 1, 2><<<dim3(EE / 128, MQ / 64, 1), blk, 0, stream>>>(
      q0, bWq, cbq, Qc, MQ, EE, EE, EE, EE, 0, 0, 0, 0, 1.0f, SLQ, qlen);
  gemm_nt<128, 128, 1, 0><<<dim3(EE / 128, MK / 128, 1), blk, 0, stream>>>(
      keysb, bWk, cbk, Kc, MK, EE, EE, EE, EE, 0, 0, 0, 0, 1.0f, SLK, qlen);
  gemm_nt<128, 128, 2, 0><<<dim3(EE / 128, MK / 128, 1), blk, 0, stream>>>(
      keysb, bWv, cbv, Vt, MK, EE, EE, EE, EE, 0, 0, 0, 0, 1.0f, SLK, qlen);

  // S = Q K^T * 1/8  (coalesced staged C write, skip invalid q tiles)
  gemm_nt<128, 128, 0, 1><<<dim3(SLK / 128, SLQ / 128, BB * HH), blk, 0, stream>>>(
      Qc, Kc, nullptr, S, SLQ, SLK, HD, HD, HD, SLK,
      (long)SLQ * HD, (long)SLK * HD, (long)SLQ * SLK, 0.125f, 0, qlen);

  // read-only softmax: stats + head-mean weights
  softmax_stats_wmean<<<dim3(BB * SLQ), blk, 0, stream>>>(S, out_w, stat, qlen);

  // PV with on-the-fly exp: split-K f32 partials + combine
  pv_cross<<<dim3(16, 32, 4), blk, 0, stream>>>(S, Vt, stat, CpF, qlen);
  pv_combine_cross<<<dim3(2048), blk, 0, stream>>>(CpF, stat, attn, qlen);

  gemm_nt<64, 128, 0, 2><<<dim3(EE / 128, MQ / 64, 1), blk, 0, stream>>>(
      attn, bWo, cbo, proj, MQ, EE, EE, EE, EE, EE, 0, 0, 0, 1.0f, SLQ, qlen);

  silu_ln_kernel<0><<<dim3(MQ), blk, 0, stream>>>(proj, q0, g_cross, b_cross, qlen, q1, 2);

  gemm_nt<64, 128, 0, 2><<<dim3(EE / 128, MQ / 64, 1), blk, 0, stream>>>(
      q1, bWf, bfb, fbuf, MQ, EE, EE, EE, EE, EE, 0, 0, 0, 1.0f, SLQ, qlen);

  silu_ln_kernel<0><<<dim3(MQ), blk, 0, stream>>>(q1, fbuf, g_ffn, b_ffn, qlen, q2, 1);

  // self projections
  gemm_nt<64, 128, 1, 2><<<dim3(EE / 128, MQ / 64, 1), blk, 0, stream>>>(
      q2, bsWq, sbq, Qc, MQ, EE, EE, EE, EE, 0, 0, 0, 0, 1.0f, SLQ, qlen);
  gemm_nt<64, 128, 1, 2><<<dim3(EE / 128, MQ / 64, 1), blk, 0, stream>>>(
      q2, bsWk, sbk, Kc, MQ, EE, EE, EE, EE, 0, 0, 0, 0, 1.0f, SLQ, qlen);
  gemm_nt<64, 128, 2, 2><<<dim3(EE / 128, MQ / 64, 1), blk, 0, stream>>>(
      q2, bsWv, sbv, Vt, MQ, EE, EE, EE, EE, 0, 0, 0, 0, 1.0f, SLQ, qlen);

  // fused self attention
  self_flash_chunk<<<dim3(16, 32, 8), blk, 0, stream>>>(Qc, Kc, Vt, OpS, mlS, qlen);
  self_combine<<<dim3(2048), blk, 0, stream>>>(OpS, mlS, attn, qlen);

  gemm_nt<64, 128, 0, 2><<<dim3(EE / 128, MQ / 64, 1), blk, 0, stream>>>(
      attn, bsWo, sbo, proj, MQ, EE, EE, EE, EE, EE, 0, 0, 0, 1.0f, SLQ, qlen);

  silu_ln_kernel<1><<<dim3(MQ), blk, 0, stream>>>(q2, proj, g_self, b_self, qlen, out_q, 1);
}